// Round 4
// baseline (387.051 us; speedup 1.0000x reference)
//
#include <hip/hip_runtime.h>
#include <stdint.h>

// SNN pipeline, algebraically fused: y2 = x @ (Wh@Wp)^T + (Wh@bp + bh), then
// T-parallel LIF scan (shadowing warm-up), pool+head.
// r7: main GEMM = asymmetric f16 emulation (A single f16 plane, B f16 hi/lo,
//     2 MFMA products). r8: Y2 stored f16. r9: 256^2 8-wave phase schedule,
//     triple-buffer LDS, counted vmcnt, XOR swizzle (conflicts->0).
// r10: one-phase-ahead ds_reads (best: 126us). r11: 1 barrier/K-step FAILED
//     (145us) -> barrier count not the limiter. r12: MFMA core switched to
//     32x32x16 f16: half the instructions (32/wave/K-step), higher ceiling
//     (2382 vs 2075 TF ubench), 2 phases x 16 MFMA, 4 barriers/K-step.
//     Granule-balance check: 32 rows x 2 kgroups under the same XOR swizzle
//     = 8 lanes per 16B-granule position = conflict-free (same as 16x16).

typedef short v8s __attribute__((ext_vector_type(8)));
typedef _Float16 v8h __attribute__((ext_vector_type(8)));
typedef float v4f __attribute__((ext_vector_type(4)));
typedef float v16f __attribute__((ext_vector_type(16)));

#define GAS __attribute__((address_space(1)))
#define LAS __attribute__((address_space(3)))

__device__ __forceinline__ unsigned short f2bf(float f) {
  unsigned int u = __float_as_uint(f);
  u += 0x7fffu + ((u >> 16) & 1u);   // round-to-nearest-even
  return (unsigned short)(u >> 16);
}
__device__ __forceinline__ float bf2f(unsigned short h) {
  return __uint_as_float(((unsigned int)h) << 16);
}
__device__ __forceinline__ unsigned short f2h(float f) {       // f32->f16 RNE
  union { _Float16 h; unsigned short u; } c;
  c.h = (_Float16)f;
  return c.u;
}
__device__ __forceinline__ float h2f(unsigned short u) {
  union { unsigned short u; _Float16 h; } c;
  c.u = u;
  return (float)c.h;
}

__device__ __forceinline__ void gld_lds16(const void* g, void* l) {
  __builtin_amdgcn_global_load_lds((const GAS void*)g, (LAS void*)l, 16, 0, 0);
}

__device__ __forceinline__ void split4(const float4 x, ushort4* h, ushort4* l) {
  h->x = f2bf(x.x); l->x = f2bf(x.x - bf2f(h->x));
  h->y = f2bf(x.y); l->y = f2bf(x.y - bf2f(h->y));
  h->z = f2bf(x.z); l->z = f2bf(x.z - bf2f(h->z));
  h->w = f2bf(x.w); l->w = f2bf(x.w - bf2f(h->w));
}

// Fused preprocessing (one launch, independent block ranges):
//  [0, 32768):      x -> f16 plane Xh           (192 MB traffic, HBM-bound)
//  [32768, 33792):  transpose+split W_proj -> WpT bf16 hi/lo
//  [33792, 34816):  split W_hid -> Wh bf16 hi/lo
//  [34816, 35072):  bc[g] = Wh[g,:].b_proj + b_hid[g]  (4 waves/block)
__global__ void __launch_bounds__(256) prep_kernel(
    const float* __restrict__ x,
    const float* __restrict__ W_proj, const float* __restrict__ W_hid,
    const float* __restrict__ b_proj, const float* __restrict__ b_hid,
    unsigned short* __restrict__ Xh,
    unsigned short* __restrict__ WpTh, unsigned short* __restrict__ WpTl,
    unsigned short* __restrict__ Whh, unsigned short* __restrict__ Whl,
    float* __restrict__ bc) {
  __shared__ float t[32][33];
  const int blk = blockIdx.x, tid = threadIdx.x;
  if (blk < 32768) {
    const int i = blk * 256 + tid;           // 8388608 float4 = 32M floats
    float4 v = ((const float4*)x)[i];
    ushort4 h;
    h.x = f2h(v.x); h.y = f2h(v.y); h.z = f2h(v.z); h.w = f2h(v.w);
    ((ushort4*)Xh)[i] = h;
  } else if (blk < 33792) {
    const int b2 = blk - 32768;
    const int tx = tid & 31, ty = tid >> 5;  // 32x8
    const int bx = b2 & 31, by = b2 >> 5;
    const int xc = bx * 32 + tx;
    const int yb = by * 32;
#pragma unroll
    for (int j = 0; j < 4; ++j) t[ty + 8 * j][tx] = W_proj[(size_t)(yb + ty + 8 * j) * 1024 + xc];
    __syncthreads();
    const int xo = yb + tx;
#pragma unroll
    for (int j = 0; j < 4; ++j) {
      const float v = t[tx][ty + 8 * j];
      const unsigned short h = f2bf(v);
      const size_t o = (size_t)(bx * 32 + ty + 8 * j) * 1024 + xo;
      WpTh[o] = h;
      WpTl[o] = f2bf(v - bf2f(h));
    }
  } else if (blk < 34816) {
    const int i = (blk - 33792) * 256 + tid; // 262144 float4 = 1M floats
    float4 v = ((const float4*)W_hid)[i];
    ushort4 h, l;
    split4(v, &h, &l);
    ((ushort4*)Whh)[i] = h;
    ((ushort4*)Whl)[i] = l;
  } else {
    const int g = (blk - 34816) * 4 + (tid >> 6);
    const int lane = tid & 63;
    const float* wr = W_hid + (size_t)g * 1024;
    float s = 0.f;
#pragma unroll
    for (int i = 0; i < 16; ++i) s += wr[lane + 64 * i] * b_proj[lane + 64 * i];
#pragma unroll
    for (int off = 32; off > 0; off >>= 1) s += __shfl_down(s, off);
    if (lane == 0) bc[g] = s + b_hid[g];
  }
}

// Weight GEMM: Wc = Wh @ WpT^T, bf16 hi/lo 3-product (near-fp32 exact),
// M=N=K=1024, 128x128 tile. Epilogue stores Wc split to f16 hi/lo (22 bits).
__global__ void __launch_bounds__(256, 2)
gemm_w(const unsigned short* __restrict__ Ah, const unsigned short* __restrict__ Al,
       const unsigned short* __restrict__ Bh, const unsigned short* __restrict__ Bl,
       unsigned short* __restrict__ outH, unsigned short* __restrict__ outL) {
  constexpr int K = 1024, N = 1024;
  __shared__ unsigned short lA[2][128 * 32];
  __shared__ unsigned short lB[2][128 * 32];

  const int tid = threadIdx.x;
  const int mt = blockIdx.x & 7, nt = blockIdx.x >> 3;  // 8x8 grid
  const int m0 = mt * 128, n0 = nt * 128;

  const int lane = tid & 63, wave = tid >> 6;
  const int wm = (wave >> 1) * 64, wn = (wave & 1) * 64;
  const int quad = lane >> 4, r = lane & 15;
  const int srow = tid >> 2, scol = (tid & 3) * 8;

  v4f acc[4][4];
#pragma unroll
  for (int i = 0; i < 4; ++i)
#pragma unroll
    for (int j = 0; j < 4; ++j) acc[i][j] = v4f{0.f, 0.f, 0.f, 0.f};

  const unsigned short* gAh = Ah + (size_t)(m0 + srow) * K + scol;
  const unsigned short* gAl = Al + (size_t)(m0 + srow) * K + scol;
  const unsigned short* gBh = Bh + (size_t)(n0 + srow) * K + scol;
  const unsigned short* gBl = Bl + (size_t)(n0 + srow) * K + scol;

  for (int kt = 0; kt < K; kt += 32) {
    gld_lds16(gAh + kt,          &lA[0][tid * 8]);
    gld_lds16(gAh + kt + 64 * K, &lA[0][tid * 8 + 64 * 32]);
    gld_lds16(gAl + kt,          &lA[1][tid * 8]);
    gld_lds16(gAl + kt + 64 * K, &lA[1][tid * 8 + 64 * 32]);
    gld_lds16(gBh + kt,          &lB[0][tid * 8]);
    gld_lds16(gBh + kt + 64 * K, &lB[0][tid * 8 + 64 * 32]);
    gld_lds16(gBl + kt,          &lB[1][tid * 8]);
    gld_lds16(gBl + kt + 64 * K, &lB[1][tid * 8 + 64 * 32]);
    __syncthreads();

    v8s ah[4], al[4], bh[4], bl[4];
#pragma unroll
    for (int i = 0; i < 4; ++i) {
      ah[i] = *(const v8s*)&lA[0][(wm + i * 16 + r) * 32 + quad * 8];
      al[i] = *(const v8s*)&lA[1][(wm + i * 16 + r) * 32 + quad * 8];
      bh[i] = *(const v8s*)&lB[0][(wn + i * 16 + r) * 32 + quad * 8];
      bl[i] = *(const v8s*)&lB[1][(wn + i * 16 + r) * 32 + quad * 8];
    }
#pragma unroll
    for (int i = 0; i < 4; ++i)
#pragma unroll
      for (int j = 0; j < 4; ++j) {
        acc[i][j] = __builtin_amdgcn_mfma_f32_16x16x32_bf16(ah[i], bh[j], acc[i][j], 0, 0, 0);
        acc[i][j] = __builtin_amdgcn_mfma_f32_16x16x32_bf16(ah[i], bl[j], acc[i][j], 0, 0, 0);
        acc[i][j] = __builtin_amdgcn_mfma_f32_16x16x32_bf16(al[i], bh[j], acc[i][j], 0, 0, 0);
      }
    __syncthreads();
  }

#pragma unroll
  for (int i = 0; i < 4; ++i)
#pragma unroll
    for (int j = 0; j < 4; ++j) {
      const int gn = n0 + wn + j * 16 + r;
#pragma unroll
      for (int q2 = 0; q2 < 4; ++q2) {
        const int gm = m0 + wm + i * 16 + quad * 4 + q2;
        const float y = acc[i][j][q2];
        const unsigned short h = f2h(y);           // f16 hi
        const size_t o = (size_t)gm * N + gn;
        outH[o] = h;
        outL[o] = f2h(y - h2f(h));                 // f16 lo
      }
    }
}

// Main GEMM: Y2(f16) = Xf16 @ Wc^T + bc. 256x256 tile, 8 waves (2Mx4N) each
// owning 128x64 = 4x2 tiles of 32x32. MFMA 32x32x16 f16: 32/wave/K-step in
// 2 phases (plane-h, plane-l) x 16. Triple-buffered LDS (3 x 48KB). Phase
// discipline: wait lgkmcnt(0) on reads issued a FULL PHASE earlier (free),
// then issue next-phase reads after the wait (outstanding lgkm <= 12).
// vmcnt counted (4 in steady state). A-frags promoted (anx->ah); B plane-h
// re-read into same regs each P1 (dead after P0) to cap VGPR < 256 total.
// Bank swizzle: phys slot = logical ^ ((row>>1)&3); 32 rows x 2 kgroups
// spread 8 lanes/granule-position -> conflict-free. Staged via inverse-
// swizzled global source + linear LDS dest (rule #21).
__global__ void __launch_bounds__(512, 2)
gemm_main(const unsigned short* __restrict__ Ah,
          const unsigned short* __restrict__ Bh, const unsigned short* __restrict__ Bl,
          const float* __restrict__ bias, unsigned short* __restrict__ outH, int M) {
  constexpr int K = 1024, N = 1024;
  __shared__ unsigned short lA[3][8192];   // 48 KB
  __shared__ unsigned short lB0[3][8192];  // 48 KB
  __shared__ unsigned short lB1[3][8192];  // 48 KB

  const int tid = threadIdx.x;
  const int band = (M >> 8) >> 3;            // 16 for M=32768
  const int c = blockIdx.x & 7, idx = blockIdx.x >> 3;   // 512 blocks, %8==0
  const int mt = c * band + (idx >> 2), nt = idx & 3;
  const int m0 = mt * 256, n0 = nt * 256;

  const int lane = tid & 63, wave = tid >> 6;
  const int wm = (wave >> 2) * 128, wn = (wave & 3) * 64;
  const int r5 = lane & 31, hi = lane >> 5;
  const int swz = (r5 >> 1) & 3;
  // k-slice ks, k-group hi -> logical slot (2ks+hi), phys = logical ^ swz
  const int s0 = ((0 | hi) ^ swz) * 8;   // ks=0
  const int s1 = ((2 | hi) ^ swz) * 8;   // ks=1
  const int arow = (wm + r5) * 32;       // + i*1024 per 32-row tile
  const int brow = (wn + r5) * 32;       // + j*1024 per 32-col tile

  // staging: thread t -> tile row t>>2, linear LDS slot t&3; global source
  // slot inverse-swizzled so the LDS image is the swizzled layout.
  const int srow = tid >> 2;                           // 0..127 (+128 call 1)
  const int sslot = (tid & 3) ^ ((tid >> 3) & 3);      // same for row+128

  const unsigned short* gA   = Ah + (size_t)(m0 + srow) * K + sslot * 8;
  const unsigned short* gB0p = Bh + (size_t)(n0 + srow) * K + sslot * 8;
  const unsigned short* gB1p = Bl + (size_t)(n0 + srow) * K + sslot * 8;

  v16f acc[4][2];
#pragma unroll
  for (int i = 0; i < 4; ++i)
#pragma unroll
    for (int j = 0; j < 2; ++j)
#pragma unroll
      for (int q = 0; q < 16; ++q) acc[i][j][q] = 0.f;

  // buffer rotation pointers: cur / nxt / nx2 (staging target)
  unsigned short *Ac = lA[0],  *An = lA[1],  *A2 = lA[2];
  unsigned short *Bc = lB0[0], *Bn = lB0[1], *B2 = lB0[2];
  unsigned short *Cc = lB1[0], *Cn = lB1[1], *C2 = lB1[2];

  // prologue: stage K-step 0 -> buf0, K-step 1 -> buf1 (6 loads each)
  gld_lds16(gA,              &Ac[tid * 8]);
  gld_lds16(gA + 128 * K,    &Ac[4096 + tid * 8]);
  gld_lds16(gB0p,            &Bc[tid * 8]);
  gld_lds16(gB0p + 128 * K,  &Bc[4096 + tid * 8]);
  gld_lds16(gB1p,            &Cc[tid * 8]);
  gld_lds16(gB1p + 128 * K,  &Cc[4096 + tid * 8]);
  gld_lds16(gA + 32,             &An[tid * 8]);
  gld_lds16(gA + 32 + 128 * K,   &An[4096 + tid * 8]);
  gld_lds16(gB0p + 32,           &Bn[tid * 8]);
  gld_lds16(gB0p + 32 + 128 * K, &Bn[4096 + tid * 8]);
  gld_lds16(gB1p + 32,           &Cn[tid * 8]);
  gld_lds16(gB1p + 32 + 128 * K, &Cn[4096 + tid * 8]);
  asm volatile("s_waitcnt vmcnt(6)" ::: "memory");   // buf0 complete
  __builtin_amdgcn_s_barrier();
  __builtin_amdgcn_sched_barrier(0);

  // preload K-step 0 operands (A all k-slices, B plane-h) from buf0
  v8h ah[4][2], anx[4][2], bh[2][2], bl[2][2];
#pragma unroll
  for (int i = 0; i < 4; ++i) {
    ah[i][0] = *(const v8h*)&Ac[arow + i * 1024 + s0];
    ah[i][1] = *(const v8h*)&Ac[arow + i * 1024 + s1];
  }
#pragma unroll
  for (int j = 0; j < 2; ++j) {
    bh[j][0] = *(const v8h*)&Bc[brow + j * 1024 + s0];
    bh[j][1] = *(const v8h*)&Bc[brow + j * 1024 + s1];
  }
  __builtin_amdgcn_sched_barrier(0);

#pragma unroll 1
  for (int t = 0; t < 32; ++t) {
    const int kp = (t + 2) * 32;
    const bool pf = (t < 30);

    // ---- P0: stage A+B0 -> nx2; confirm prev stages + all prior reads;
    //          read bl(cur); MFMA plane-h ----
    if (pf) {
      gld_lds16(gA + kp,            &A2[tid * 8]);
      gld_lds16(gA + kp + 128 * K,  &A2[4096 + tid * 8]);
      gld_lds16(gB0p + kp,           &B2[tid * 8]);
      gld_lds16(gB0p + kp + 128 * K, &B2[4096 + tid * 8]);
    }
    __builtin_amdgcn_sched_barrier(0);
    __builtin_amdgcn_s_barrier();
    // vmcnt: drain prev iter's 6 (buffer nxt ready for P1 reads), keep this
    // iter's 4. lgkmcnt(0): ah/bh (read last phase) confirmed - free.
    if (pf) asm volatile("s_waitcnt vmcnt(4) lgkmcnt(0)" ::: "memory");
    else    asm volatile("s_waitcnt vmcnt(0) lgkmcnt(0)" ::: "memory");
    __builtin_amdgcn_sched_barrier(0);
#pragma unroll
    for (int j = 0; j < 2; ++j) {
      bl[j][0] = *(const v8h*)&Cc[brow + j * 1024 + s0];
      bl[j][1] = *(const v8h*)&Cc[brow + j * 1024 + s1];
    }
    __builtin_amdgcn_s_setprio(1);
#pragma unroll
    for (int i = 0; i < 4; ++i)
#pragma unroll
      for (int j = 0; j < 2; ++j) {
        acc[i][j] = __builtin_amdgcn_mfma_f32_32x32x16_f16(ah[i][0], bh[j][0], acc[i][j], 0, 0, 0);
        acc[i][j] = __builtin_amdgcn_mfma_f32_32x32x16_f16(ah[i][1], bh[j][1], acc[i][j], 0, 0, 0);
      }
    __builtin_amdgcn_s_setprio(0);
    __builtin_amdgcn_sched_barrier(0);
    __builtin_amdgcn_s_barrier();

    // ---- P1: stage B1 -> nx2; confirm bl; read next K-step's A (->anx)
    //          and B plane-h (->bh, dead after P0); MFMA plane-l ----
    if (pf) {
      gld_lds16(gB1p + kp,           &C2[tid * 8]);
      gld_lds16(gB1p + kp + 128 * K, &C2[4096 + tid * 8]);
    }
    __builtin_amdgcn_sched_barrier(0);
    __builtin_amdgcn_s_barrier();
    asm volatile("s_waitcnt lgkmcnt(0)" ::: "memory");   // bl confirmed
    __builtin_amdgcn_sched_barrier(0);
    if (t < 31) {
#pragma unroll
      for (int i = 0; i < 4; ++i) {
        anx[i][0] = *(const v8h*)&An[arow + i * 1024 + s0];
        anx[i][1] = *(const v8h*)&An[arow + i * 1024 + s1];
      }
#pragma unroll
      for (int j = 0; j < 2; ++j) {
        bh[j][0] = *(const v8h*)&Bn[brow + j * 1024 + s0];
        bh[j][1] = *(const v8h*)&Bn[brow + j * 1024 + s1];
      }
    }
    __builtin_amdgcn_s_setprio(1);
#pragma unroll
    for (int i = 0; i < 4; ++i)
#pragma unroll
      for (int j = 0; j < 2; ++j) {
        acc[i][j] = __builtin_amdgcn_mfma_f32_32x32x16_f16(ah[i][0], bl[j][0], acc[i][j], 0, 0, 0);
        acc[i][j] = __builtin_amdgcn_mfma_f32_32x32x16_f16(ah[i][1], bl[j][1], acc[i][j], 0, 0, 0);
      }
    __builtin_amdgcn_s_setprio(0);
    __builtin_amdgcn_sched_barrier(0);
    __builtin_amdgcn_s_barrier();

    // promote A-fragments; rotate buffers
#pragma unroll
    for (int i = 0; i < 4; ++i) { ah[i][0] = anx[i][0]; ah[i][1] = anx[i][1]; }
    unsigned short* tp;
    tp = Ac; Ac = An; An = A2; A2 = tp;
    tp = Bc; Bc = Bn; Bn = B2; B2 = tp;
    tp = Cc; Cc = Cn; Cn = C2; C2 = tp;
  }

  // epilogue: C/D 32x32: col = lane&31, row = (q&3) + 8*(q>>2) + 4*hi
  float bv[2];
#pragma unroll
  for (int j = 0; j < 2; ++j) bv[j] = bias[n0 + wn + j * 32 + r5];
#pragma unroll
  for (int i = 0; i < 4; ++i)
#pragma unroll
    for (int j = 0; j < 2; ++j) {
      const int gn = n0 + wn + j * 32 + r5;
#pragma unroll
      for (int q = 0; q < 16; ++q) {
        const int gm = m0 + wm + i * 32 + (q & 3) + 8 * (q >> 2) + 4 * hi;
        outH[(size_t)gm * N + gn] = f2h(acc[i][j][q] + bv[j]);
      }
    }
}

// T-parallel LIF over f16 y2: 8 chunks of 128 steps, 32-step shadowing
// warm-up (state contracts x0.5/step; 2^-32 residual ~1e-9 -> no flips).
__global__ void __launch_bounds__(256) lif_part_kernel(const unsigned short* __restrict__ y2,
                                                       float* __restrict__ part) {
  const int idx = blockIdx.x * 256 + threadIdx.x;  // chunk*32768 + ch
  const int ch = idx & 32767, chunk = idx >> 15;
  const unsigned short* p = y2 + ((size_t)(ch >> 10) << 20) + (ch & 1023);
  const int t0 = chunk << 7;
  float v = 0.f;
  if (chunk) {  // uniform per wave (32768 % 64 == 0)
    const unsigned short* pw = p + (size_t)(t0 - 32) * 1024;
    for (int b = 0; b < 32; b += 16) {
      float x[16];
#pragma unroll
      for (int i = 0; i < 16; ++i) x[i] = h2f(pw[(size_t)(b + i) * 1024]);
#pragma unroll
      for (int i = 0; i < 16; ++i) {
        v += (x[i] - v) * 0.5f;
        if (v >= 1.0f) v -= 1.0f;
      }
    }
  }
  float cnt = 0.f;
  const unsigned short* pm = p + (size_t)t0 * 1024;
  for (int b = 0; b < 128; b += 16) {
    float x[16];
#pragma unroll
    for (int i = 0; i < 16; ++i) x[i] = h2f(pm[(size_t)(b + i) * 1024]);
#pragma unroll
    for (int i = 0; i < 16; ++i) {
      v += (x[i] - v) * 0.5f;              // exact reference op order
      float s = (v >= 1.0f) ? 1.0f : 0.0f;
      cnt += s;
      v -= s;
    }
  }
  part[idx] = cnt;
}

// out[b,o] = (sum_c part[c][b,:]).W_out[o,:]/1024 + b_out[o]; one wave each.
// part holds integer spike counts -> cross-chunk sum exact in any order.
__global__ void __launch_bounds__(64) head_kernel(const float* __restrict__ part,
                                                  const float* __restrict__ W_out,
                                                  const float* __restrict__ b_out,
                                                  float* __restrict__ out) {
  int blk = blockIdx.x;          // 0..319
  int b = blk / 10, o = blk % 10;
  int lane = threadIdx.x;
  const float* wr = W_out + o * 1024;
  float s = 0.f;
#pragma unroll
  for (int i = 0; i < 16; ++i) {
    const int ch = b * 1024 + lane + 64 * i;
    float p = 0.f;
#pragma unroll
    for (int c = 0; c < 8; ++c) p += part[c * 32768 + ch];
    s += p * wr[lane + 64 * i];
  }
#pragma unroll
  for (int off = 32; off > 0; off >>= 1) s += __shfl_down(s, off);
  if (lane == 0) out[b * 10 + o] = s * (1.0f / 1024.0f) + b_out[o];
}

extern "C" void kernel_launch(void* const* d_in, const int* in_sizes, int n_in,
                              void* d_out, int out_size, void* d_ws, size_t ws_size,
                              hipStream_t stream) {
  const float* x      = (const float*)d_in[0];
  const float* W_proj = (const float*)d_in[1];
  const float* b_proj = (const float*)d_in[2];
  const float* W_hid  = (const float*)d_in[3];
  const float* b_hid  = (const float*)d_in[4];
  const float* W_out  = (const float*)d_in[5];
  const float* b_out  = (const float*)d_in[6];
  float* out = (float*)d_out;

  const int M = 32768;  // B*T

  // Workspace (~143 MB): Xh f16 [64M] | Y2 f16 [64M] | weights | bc | part
  char* ws = (char*)d_ws;
  unsigned short* Xh   = (unsigned short*)(ws);
  unsigned short* Y2   = (unsigned short*)(ws + 67108864);
  char* base = ws + 134217728;
  unsigned short* WpTh = (unsigned short*)(base);             // bf16
  unsigned short* WpTl = (unsigned short*)(base + 2097152);
  unsigned short* Whh  = (unsigned short*)(base + 4194304);
  unsigned short* Whl  = (unsigned short*)(base + 6291456);
  unsigned short* Wch  = (unsigned short*)(base + 8388608);   // f16
  unsigned short* Wcl  = (unsigned short*)(base + 10485760);
  float*           bc  = (float*)(base + 12582912);
  float*          part = (float*)(base + 12582912 + 65536);

  prep_kernel<<<35072, 256, 0, stream>>>(x, W_proj, W_hid, b_proj, b_hid,
                                         Xh, WpTh, WpTl, Whh, Whl, bc);
  // Wc[g,d] = sum_h Wh[g,h] * WpT[d,h], stored as f16 hi/lo
  gemm_w<<<64, 256, 0, stream>>>(Whh, Whl, WpTh, WpTl, Wch, Wcl);
  gemm_main<<<512, 512, 0, stream>>>(Xh, Wch, Wcl, bc, Y2, M);
  lif_part_kernel<<<1024, 256, 0, stream>>>(Y2, part);
  head_kernel<<<320, 64, 0, stream>>>(part, W_out, b_out, out);
}

// Round 5
// 378.713 us; speedup vs baseline: 1.0220x; 1.0220x over previous
//
#include <hip/hip_runtime.h>
#include <stdint.h>

// SNN pipeline, algebraically fused: y2 = x @ (Wh@Wp)^T + (Wh@bp + bh), then
// T-parallel LIF scan (shadowing warm-up), pool+head.
// r7: main GEMM = asymmetric f16 emulation (A single f16 plane, B f16 hi/lo,
//     2 MFMA products). r8: Y2 stored f16. r9: 256^2 8-wave phase schedule,
//     triple-buffer LDS, counted vmcnt, XOR swizzle (conflicts->0).
// r10: one-phase-ahead ds_reads -> BEST gemm_main (126us, MfmaUtil 47,
//     conflicts 0). r11: 1-barrier free-run FAILED (145us). r12: 32x32x16
//     FAILED (143us, 8.4M bank conflicts -> granule model wrong).
// r13: gemm_main reverted to r10-exact; lif_part vectorized 4 ch/thread
//     (ushort4 loads, was 128 scalar 2B loads/thread = Common-mistake #2).

typedef short v8s __attribute__((ext_vector_type(8)));
typedef _Float16 v8h __attribute__((ext_vector_type(8)));
typedef float v4f __attribute__((ext_vector_type(4)));

#define GAS __attribute__((address_space(1)))
#define LAS __attribute__((address_space(3)))

__device__ __forceinline__ unsigned short f2bf(float f) {
  unsigned int u = __float_as_uint(f);
  u += 0x7fffu + ((u >> 16) & 1u);   // round-to-nearest-even
  return (unsigned short)(u >> 16);
}
__device__ __forceinline__ float bf2f(unsigned short h) {
  return __uint_as_float(((unsigned int)h) << 16);
}
__device__ __forceinline__ unsigned short f2h(float f) {       // f32->f16 RNE
  union { _Float16 h; unsigned short u; } c;
  c.h = (_Float16)f;
  return c.u;
}
__device__ __forceinline__ float h2f(unsigned short u) {
  union { unsigned short u; _Float16 h; } c;
  c.u = u;
  return (float)c.h;
}

__device__ __forceinline__ void gld_lds16(const void* g, void* l) {
  __builtin_amdgcn_global_load_lds((const GAS void*)g, (LAS void*)l, 16, 0, 0);
}

__device__ __forceinline__ void split4(const float4 x, ushort4* h, ushort4* l) {
  h->x = f2bf(x.x); l->x = f2bf(x.x - bf2f(h->x));
  h->y = f2bf(x.y); l->y = f2bf(x.y - bf2f(h->y));
  h->z = f2bf(x.z); l->z = f2bf(x.z - bf2f(h->z));
  h->w = f2bf(x.w); l->w = f2bf(x.w - bf2f(h->w));
}

// Fused preprocessing (one launch, independent block ranges):
//  [0, 32768):      x -> f16 plane Xh           (192 MB traffic, HBM-bound)
//  [32768, 33792):  transpose+split W_proj -> WpT bf16 hi/lo
//  [33792, 34816):  split W_hid -> Wh bf16 hi/lo
//  [34816, 35072):  bc[g] = Wh[g,:].b_proj + b_hid[g]  (4 waves/block)
__global__ void __launch_bounds__(256) prep_kernel(
    const float* __restrict__ x,
    const float* __restrict__ W_proj, const float* __restrict__ W_hid,
    const float* __restrict__ b_proj, const float* __restrict__ b_hid,
    unsigned short* __restrict__ Xh,
    unsigned short* __restrict__ WpTh, unsigned short* __restrict__ WpTl,
    unsigned short* __restrict__ Whh, unsigned short* __restrict__ Whl,
    float* __restrict__ bc) {
  __shared__ float t[32][33];
  const int blk = blockIdx.x, tid = threadIdx.x;
  if (blk < 32768) {
    const int i = blk * 256 + tid;           // 8388608 float4 = 32M floats
    float4 v = ((const float4*)x)[i];
    ushort4 h;
    h.x = f2h(v.x); h.y = f2h(v.y); h.z = f2h(v.z); h.w = f2h(v.w);
    ((ushort4*)Xh)[i] = h;
  } else if (blk < 33792) {
    const int b2 = blk - 32768;
    const int tx = tid & 31, ty = tid >> 5;  // 32x8
    const int bx = b2 & 31, by = b2 >> 5;
    const int xc = bx * 32 + tx;
    const int yb = by * 32;
#pragma unroll
    for (int j = 0; j < 4; ++j) t[ty + 8 * j][tx] = W_proj[(size_t)(yb + ty + 8 * j) * 1024 + xc];
    __syncthreads();
    const int xo = yb + tx;
#pragma unroll
    for (int j = 0; j < 4; ++j) {
      const float v = t[tx][ty + 8 * j];
      const unsigned short h = f2bf(v);
      const size_t o = (size_t)(bx * 32 + ty + 8 * j) * 1024 + xo;
      WpTh[o] = h;
      WpTl[o] = f2bf(v - bf2f(h));
    }
  } else if (blk < 34816) {
    const int i = (blk - 33792) * 256 + tid; // 262144 float4 = 1M floats
    float4 v = ((const float4*)W_hid)[i];
    ushort4 h, l;
    split4(v, &h, &l);
    ((ushort4*)Whh)[i] = h;
    ((ushort4*)Whl)[i] = l;
  } else {
    const int g = (blk - 34816) * 4 + (tid >> 6);
    const int lane = tid & 63;
    const float* wr = W_hid + (size_t)g * 1024;
    float s = 0.f;
#pragma unroll
    for (int i = 0; i < 16; ++i) s += wr[lane + 64 * i] * b_proj[lane + 64 * i];
#pragma unroll
    for (int off = 32; off > 0; off >>= 1) s += __shfl_down(s, off);
    if (lane == 0) bc[g] = s + b_hid[g];
  }
}

// Weight GEMM: Wc = Wh @ WpT^T, bf16 hi/lo 3-product (near-fp32 exact),
// M=N=K=1024, 128x128 tile. Epilogue stores Wc split to f16 hi/lo (22 bits).
__global__ void __launch_bounds__(256, 2)
gemm_w(const unsigned short* __restrict__ Ah, const unsigned short* __restrict__ Al,
       const unsigned short* __restrict__ Bh, const unsigned short* __restrict__ Bl,
       unsigned short* __restrict__ outH, unsigned short* __restrict__ outL) {
  constexpr int K = 1024, N = 1024;
  __shared__ unsigned short lA[2][128 * 32];
  __shared__ unsigned short lB[2][128 * 32];

  const int tid = threadIdx.x;
  const int mt = blockIdx.x & 7, nt = blockIdx.x >> 3;  // 8x8 grid
  const int m0 = mt * 128, n0 = nt * 128;

  const int lane = tid & 63, wave = tid >> 6;
  const int wm = (wave >> 1) * 64, wn = (wave & 1) * 64;
  const int quad = lane >> 4, r = lane & 15;
  const int srow = tid >> 2, scol = (tid & 3) * 8;

  v4f acc[4][4];
#pragma unroll
  for (int i = 0; i < 4; ++i)
#pragma unroll
    for (int j = 0; j < 4; ++j) acc[i][j] = v4f{0.f, 0.f, 0.f, 0.f};

  const unsigned short* gAh = Ah + (size_t)(m0 + srow) * K + scol;
  const unsigned short* gAl = Al + (size_t)(m0 + srow) * K + scol;
  const unsigned short* gBh = Bh + (size_t)(n0 + srow) * K + scol;
  const unsigned short* gBl = Bl + (size_t)(n0 + srow) * K + scol;

  for (int kt = 0; kt < K; kt += 32) {
    gld_lds16(gAh + kt,          &lA[0][tid * 8]);
    gld_lds16(gAh + kt + 64 * K, &lA[0][tid * 8 + 64 * 32]);
    gld_lds16(gAl + kt,          &lA[1][tid * 8]);
    gld_lds16(gAl + kt + 64 * K, &lA[1][tid * 8 + 64 * 32]);
    gld_lds16(gBh + kt,          &lB[0][tid * 8]);
    gld_lds16(gBh + kt + 64 * K, &lB[0][tid * 8 + 64 * 32]);
    gld_lds16(gBl + kt,          &lB[1][tid * 8]);
    gld_lds16(gBl + kt + 64 * K, &lB[1][tid * 8 + 64 * 32]);
    __syncthreads();

    v8s ah[4], al[4], bh[4], bl[4];
#pragma unroll
    for (int i = 0; i < 4; ++i) {
      ah[i] = *(const v8s*)&lA[0][(wm + i * 16 + r) * 32 + quad * 8];
      al[i] = *(const v8s*)&lA[1][(wm + i * 16 + r) * 32 + quad * 8];
      bh[i] = *(const v8s*)&lB[0][(wn + i * 16 + r) * 32 + quad * 8];
      bl[i] = *(const v8s*)&lB[1][(wn + i * 16 + r) * 32 + quad * 8];
    }
#pragma unroll
    for (int i = 0; i < 4; ++i)
#pragma unroll
      for (int j = 0; j < 4; ++j) {
        acc[i][j] = __builtin_amdgcn_mfma_f32_16x16x32_bf16(ah[i], bh[j], acc[i][j], 0, 0, 0);
        acc[i][j] = __builtin_amdgcn_mfma_f32_16x16x32_bf16(ah[i], bl[j], acc[i][j], 0, 0, 0);
        acc[i][j] = __builtin_amdgcn_mfma_f32_16x16x32_bf16(al[i], bh[j], acc[i][j], 0, 0, 0);
      }
    __syncthreads();
  }

#pragma unroll
  for (int i = 0; i < 4; ++i)
#pragma unroll
    for (int j = 0; j < 4; ++j) {
      const int gn = n0 + wn + j * 16 + r;
#pragma unroll
      for (int q2 = 0; q2 < 4; ++q2) {
        const int gm = m0 + wm + i * 16 + quad * 4 + q2;
        const float y = acc[i][j][q2];
        const unsigned short h = f2h(y);           // f16 hi
        const size_t o = (size_t)gm * N + gn;
        outH[o] = h;
        outL[o] = f2h(y - h2f(h));                 // f16 lo
      }
    }
}

// Main GEMM: Y2(f16) = Xf16 @ Wc^T + bc. 256x256 tile, 8 waves (2Mx4N) each
// owning 128x64. BK=32, both B planes per K-step -> 64 MFMA/wave/K-step split
// into 4 phases x 16 MFMA. Triple-buffered LDS (3 x 48KB). ds_reads issued
// ONE PHASE AHEAD of their MFMA use, with counted lgkmcnt(N) (N = reads just
// issued) so LDS latency hides under MFMA. Counted vmcnt(4) at P1 confirms
// buffer nxt one phase before P2's cross-K-step prefetch reads it. Bank
// swizzle via pre-swizzled global source + swizzled ds_read addr (rule #21).
// [r10-exact: best measured 126us / MfmaUtil 47 / conflicts 0]
__global__ void __launch_bounds__(512, 2)
gemm_main(const unsigned short* __restrict__ Ah,
          const unsigned short* __restrict__ Bh, const unsigned short* __restrict__ Bl,
          const float* __restrict__ bias, unsigned short* __restrict__ outH, int M) {
  constexpr int K = 1024, N = 1024;
  __shared__ unsigned short lA[3][8192];   // 48 KB
  __shared__ unsigned short lB0[3][8192];  // 48 KB
  __shared__ unsigned short lB1[3][8192];  // 48 KB

  const int tid = threadIdx.x;
  const int band = (M >> 8) >> 3;            // 16 for M=32768
  const int c = blockIdx.x & 7, idx = blockIdx.x >> 3;   // 512 blocks, %8==0
  const int mt = c * band + (idx >> 2), nt = idx & 3;
  const int m0 = mt * 256, n0 = nt * 256;

  const int lane = tid & 63, wave = tid >> 6;
  const int wm = (wave >> 2) * 128, wn = (wave & 3) * 64;
  const int quad = lane >> 4, r = lane & 15;
  // swizzled read column (shorts): physical slot = quad ^ ((row>>1)&3)
  const int cs = (quad ^ ((r >> 1) & 3)) * 8;
  const int aoff = (wm + r) * 32 + cs;   // + i*512 per fragment
  const int boff = (wn + r) * 32 + cs;   // + j*512 per fragment

  // staging: thread t -> tile row t>>2, linear LDS slot t&3; global source
  // slot inverse-swizzled so the LDS image is the swizzled layout.
  const int srow = tid >> 2;                           // 0..127 (+128 call 1)
  const int sslot = (tid & 3) ^ ((tid >> 3) & 3);      // same for row+128

  const unsigned short* gA   = Ah + (size_t)(m0 + srow) * K + sslot * 8;
  const unsigned short* gB0p = Bh + (size_t)(n0 + srow) * K + sslot * 8;
  const unsigned short* gB1p = Bl + (size_t)(n0 + srow) * K + sslot * 8;

  v4f acc[8][4];
#pragma unroll
  for (int i = 0; i < 8; ++i)
#pragma unroll
    for (int j = 0; j < 4; ++j) acc[i][j] = v4f{0.f, 0.f, 0.f, 0.f};

  // buffer rotation pointers: cur / nxt / nx2 (staging target)
  unsigned short *Ac = lA[0],  *An = lA[1],  *A2 = lA[2];
  unsigned short *Bc = lB0[0], *Bn = lB0[1], *B2 = lB0[2];
  unsigned short *Cc = lB1[0], *Cn = lB1[1], *C2 = lB1[2];

  // prologue: stage K-step 0 -> buf0, K-step 1 -> buf1 (6 loads each)
  gld_lds16(gA,              &Ac[tid * 8]);
  gld_lds16(gA + 128 * K,    &Ac[4096 + tid * 8]);
  gld_lds16(gB0p,            &Bc[tid * 8]);
  gld_lds16(gB0p + 128 * K,  &Bc[4096 + tid * 8]);
  gld_lds16(gB1p,            &Cc[tid * 8]);
  gld_lds16(gB1p + 128 * K,  &Cc[4096 + tid * 8]);
  gld_lds16(gA + 32,             &An[tid * 8]);
  gld_lds16(gA + 32 + 128 * K,   &An[4096 + tid * 8]);
  gld_lds16(gB0p + 32,           &Bn[tid * 8]);
  gld_lds16(gB0p + 32 + 128 * K, &Bn[4096 + tid * 8]);
  gld_lds16(gB1p + 32,           &Cn[tid * 8]);
  gld_lds16(gB1p + 32 + 128 * K, &Cn[4096 + tid * 8]);
  asm volatile("s_waitcnt vmcnt(6)" ::: "memory");   // buf0 complete
  __builtin_amdgcn_s_barrier();
  __builtin_amdgcn_sched_barrier(0);

  // preload P0 operands of K-step 0 from buf0
  v8h ah[4], bh[4];
#pragma unroll
  for (int i = 0; i < 4; ++i) ah[i] = *(const v8h*)&Ac[aoff + i * 512];
#pragma unroll
  for (int j = 0; j < 4; ++j) bh[j] = *(const v8h*)&Bc[boff + j * 512];
  __builtin_amdgcn_sched_barrier(0);

#pragma unroll 1
  for (int t = 0; t < 32; ++t) {
    const int kp = (t + 2) * 32;
    const bool pf = (t < 30);
    v8h bl[4], ah2[4], anx[4], bnx[4];

    // ---- P0: read bl(cur); stage A -> nx2; MFMA ah x bh ----
#pragma unroll
    for (int j = 0; j < 4; ++j) bl[j] = *(const v8h*)&Cc[boff + j * 512];
    if (pf) {
      gld_lds16(gA + kp,           &A2[tid * 8]);
      gld_lds16(gA + kp + 128 * K, &A2[4096 + tid * 8]);
    }
    __builtin_amdgcn_sched_barrier(0);
    __builtin_amdgcn_s_barrier();
    asm volatile("s_waitcnt lgkmcnt(4)" ::: "memory");  // ah,bh ready; bl in flight
    __builtin_amdgcn_sched_barrier(0);
    __builtin_amdgcn_s_setprio(1);
#pragma unroll
    for (int i = 0; i < 4; ++i)
#pragma unroll
      for (int j = 0; j < 4; ++j)
        acc[i][j] = __builtin_amdgcn_mfma_f32_16x16x32_f16(ah[i], bh[j], acc[i][j], 0, 0, 0);
    __builtin_amdgcn_s_setprio(0);
    __builtin_amdgcn_sched_barrier(0);
    __builtin_amdgcn_s_barrier();

    // ---- P1: read ah2(cur); stage B0 -> nx2; MFMA ah x bl ----
#pragma unroll
    for (int i = 0; i < 4; ++i) ah2[i] = *(const v8h*)&Ac[aoff + (4 + i) * 512];
    if (pf) {
      gld_lds16(gB0p + kp,           &B2[tid * 8]);
      gld_lds16(gB0p + kp + 128 * K, &B2[4096 + tid * 8]);
    }
    __builtin_amdgcn_sched_barrier(0);
    __builtin_amdgcn_s_barrier();
    // vmcnt(4): the 4 newest are this iter's A+B0 stages; everything older
    // (buffer nxt's 6 loads) confirmed -> P2 may read buf nxt after barrier.
    asm volatile("s_waitcnt vmcnt(4) lgkmcnt(4)" ::: "memory");  // bl ready
    __builtin_amdgcn_sched_barrier(0);
    __builtin_amdgcn_s_setprio(1);
#pragma unroll
    for (int i = 0; i < 4; ++i)
#pragma unroll
      for (int j = 0; j < 4; ++j)
        acc[i][j] = __builtin_amdgcn_mfma_f32_16x16x32_f16(ah[i], bl[j], acc[i][j], 0, 0, 0);
    __builtin_amdgcn_s_setprio(0);
    __builtin_amdgcn_sched_barrier(0);
    __builtin_amdgcn_s_barrier();

    // ---- P2: read next K-step's ah,bh from buf nxt; stage B1 -> nx2;
    //          MFMA ah2 x bh ----
#pragma unroll
    for (int i = 0; i < 4; ++i) anx[i] = *(const v8h*)&An[aoff + i * 512];
#pragma unroll
    for (int j = 0; j < 4; ++j) bnx[j] = *(const v8h*)&Bn[boff + j * 512];
    if (pf) {
      gld_lds16(gB1p + kp,           &C2[tid * 8]);
      gld_lds16(gB1p + kp + 128 * K, &C2[4096 + tid * 8]);
    }
    __builtin_amdgcn_sched_barrier(0);
    __builtin_amdgcn_s_barrier();
    asm volatile("s_waitcnt lgkmcnt(8)" ::: "memory");  // ah2 ready; anx,bnx in flight
    __builtin_amdgcn_sched_barrier(0);
    __builtin_amdgcn_s_setprio(1);
#pragma unroll
    for (int i = 0; i < 4; ++i)
#pragma unroll
      for (int j = 0; j < 4; ++j)
        acc[4 + i][j] = __builtin_amdgcn_mfma_f32_16x16x32_f16(ah2[i], bh[j], acc[4 + i][j], 0, 0, 0);
    __builtin_amdgcn_s_setprio(0);
    __builtin_amdgcn_sched_barrier(0);
    __builtin_amdgcn_s_barrier();

    // ---- P3: MFMA ah2 x bl (all operands confirmed earlier) ----
    __builtin_amdgcn_s_setprio(1);
#pragma unroll
    for (int i = 0; i < 4; ++i)
#pragma unroll
      for (int j = 0; j < 4; ++j)
        acc[4 + i][j] = __builtin_amdgcn_mfma_f32_16x16x32_f16(ah2[i], bl[j], acc[4 + i][j], 0, 0, 0);
    __builtin_amdgcn_s_setprio(0);
    __builtin_amdgcn_sched_barrier(0);
    __builtin_amdgcn_s_barrier();

    // rotate buffers; promote prefetched operands
    unsigned short* tp;
    tp = Ac; Ac = An; An = A2; A2 = tp;
    tp = Bc; Bc = Bn; Bn = B2; B2 = tp;
    tp = Cc; Cc = Cn; Cn = C2; C2 = tp;
#pragma unroll
    for (int i = 0; i < 4; ++i) { ah[i] = anx[i]; bh[i] = bnx[i]; }
  }

  // epilogue: C[m = quad*4+q2][n = lane&15]; store f16 with bias
  float bv[4];
#pragma unroll
  for (int j = 0; j < 4; ++j) bv[j] = bias[n0 + wn + j * 16 + r];
#pragma unroll
  for (int i = 0; i < 8; ++i)
#pragma unroll
    for (int j = 0; j < 4; ++j) {
      const int gn = n0 + wn + j * 16 + r;
#pragma unroll
      for (int q2 = 0; q2 < 4; ++q2) {
        const int gm = m0 + wm + i * 16 + quad * 4 + q2;
        outH[(size_t)gm * N + gn] = f2h(acc[i][j][q2] + bv[j]);
      }
    }
}

// T-parallel LIF over f16 y2: 8 chunks of 128 steps, 32-step shadowing
// warm-up (state contracts x0.5/step; 2^-32 residual ~1e-9 -> no flips).
// r13: 4 channels/thread, ushort4 (8B) loads -- was 128 scalar 2B loads per
// thread (Common-mistake #2). Per-channel op order identical to scalar ver.
__global__ void __launch_bounds__(256) lif_part_kernel(const unsigned short* __restrict__ y2,
                                                       float* __restrict__ part) {
  const int gid = blockIdx.x * 256 + threadIdx.x;   // 65536 threads
  const int chunk = gid >> 13;                      // 8192 threads/chunk
  const int c4 = (gid & 8191) << 2;                 // base channel, %4==0
  const unsigned short* p = y2 + ((size_t)(c4 >> 10) << 20) + (c4 & 1023);
  const int t0 = chunk << 7;
  float v0 = 0.f, v1 = 0.f, v2 = 0.f, v3 = 0.f;
  if (chunk) {  // uniform per wave (8192 % 64 == 0)
    const unsigned short* pw = p + (size_t)(t0 - 32) * 1024;
    for (int b = 0; b < 32; b += 16) {
      ushort4 x[16];
#pragma unroll
      for (int i = 0; i < 16; ++i) x[i] = *(const ushort4*)&pw[(size_t)(b + i) * 1024];
#pragma unroll
      for (int i = 0; i < 16; ++i) {
        v0 += (h2f(x[i].x) - v0) * 0.5f; if (v0 >= 1.0f) v0 -= 1.0f;
        v1 += (h2f(x[i].y) - v1) * 0.5f; if (v1 >= 1.0f) v1 -= 1.0f;
        v2 += (h2f(x[i].z) - v2) * 0.5f; if (v2 >= 1.0f) v2 -= 1.0f;
        v3 += (h2f(x[i].w) - v3) * 0.5f; if (v3 >= 1.0f) v3 -= 1.0f;
      }
    }
  }
  float c0 = 0.f, c1 = 0.f, c2 = 0.f, c3 = 0.f;
  const unsigned short* pm = p + (size_t)t0 * 1024;
  for (int b = 0; b < 128; b += 16) {
    ushort4 x[16];
#pragma unroll
    for (int i = 0; i < 16; ++i) x[i] = *(const ushort4*)&pm[(size_t)(b + i) * 1024];
#pragma unroll
    for (int i = 0; i < 16; ++i) {
      float s;
      v0 += (h2f(x[i].x) - v0) * 0.5f; s = (v0 >= 1.0f) ? 1.0f : 0.0f; c0 += s; v0 -= s;
      v1 += (h2f(x[i].y) - v1) * 0.5f; s = (v1 >= 1.0f) ? 1.0f : 0.0f; c1 += s; v1 -= s;
      v2 += (h2f(x[i].z) - v2) * 0.5f; s = (v2 >= 1.0f) ? 1.0f : 0.0f; c2 += s; v2 -= s;
      v3 += (h2f(x[i].w) - v3) * 0.5f; s = (v3 >= 1.0f) ? 1.0f : 0.0f; c3 += s; v3 -= s;
    }
  }
  float4 o; o.x = c0; o.y = c1; o.z = c2; o.w = c3;
  *(float4*)&part[(size_t)chunk * 32768 + c4] = o;
}

// out[b,o] = (sum_c part[c][b,:]).W_out[o,:]/1024 + b_out[o]; one wave each.
// part holds integer spike counts -> cross-chunk sum exact in any order.
__global__ void __launch_bounds__(64) head_kernel(const float* __restrict__ part,
                                                  const float* __restrict__ W_out,
                                                  const float* __restrict__ b_out,
                                                  float* __restrict__ out) {
  int blk = blockIdx.x;          // 0..319
  int b = blk / 10, o = blk % 10;
  int lane = threadIdx.x;
  const float* wr = W_out + o * 1024;
  float s = 0.f;
#pragma unroll
  for (int i = 0; i < 16; ++i) {
    const int ch = b * 1024 + lane + 64 * i;
    float p = 0.f;
#pragma unroll
    for (int c = 0; c < 8; ++c) p += part[c * 32768 + ch];
    s += p * wr[lane + 64 * i];
  }
#pragma unroll
  for (int off = 32; off > 0; off >>= 1) s += __shfl_down(s, off);
  if (lane == 0) out[b * 10 + o] = s * (1.0f / 1024.0f) + b_out[o];
}

extern "C" void kernel_launch(void* const* d_in, const int* in_sizes, int n_in,
                              void* d_out, int out_size, void* d_ws, size_t ws_size,
                              hipStream_t stream) {
  const float* x      = (const float*)d_in[0];
  const float* W_proj = (const float*)d_in[1];
  const float* b_proj = (const float*)d_in[2];
  const float* W_hid  = (const float*)d_in[3];
  const float* b_hid  = (const float*)d_in[4];
  const float* W_out  = (const float*)d_in[5];
  const float* b_out  = (const float*)d_in[6];
  float* out = (float*)d_out;

  const int M = 32768;  // B*T

  // Workspace (~143 MB): Xh f16 [64M] | Y2 f16 [64M] | weights | bc | part
  char* ws = (char*)d_ws;
  unsigned short* Xh   = (unsigned short*)(ws);
  unsigned short* Y2   = (unsigned short*)(ws + 67108864);
  char* base = ws + 134217728;
  unsigned short* WpTh = (unsigned short*)(base);             // bf16
  unsigned short* WpTl = (unsigned short*)(base + 2097152);
  unsigned short* Whh  = (unsigned short*)(base + 4194304);
  unsigned short* Whl  = (unsigned short*)(base + 6291456);
  unsigned short* Wch  = (unsigned short*)(base + 8388608);   // f16
  unsigned short* Wcl  = (unsigned short*)(base + 10485760);
  float*           bc  = (float*)(base + 12582912);
  float*          part = (float*)(base + 12582912 + 65536);

  prep_kernel<<<35072, 256, 0, stream>>>(x, W_proj, W_hid, b_proj, b_hid,
                                         Xh, WpTh, WpTl, Whh, Whl, bc);
  // Wc[g,d] = sum_h Wh[g,h] * WpT[d,h], stored as f16 hi/lo
  gemm_w<<<64, 256, 0, stream>>>(Whh, Whl, WpTh, WpTl, Wch, Wcl);
  gemm_main<<<512, 512, 0, stream>>>(Xh, Wch, Wcl, bc, Y2, M);
  lif_part_kernel<<<256, 256, 0, stream>>>(Y2, part);
  head_kernel<<<320, 64, 0, stream>>>(part, W_out, b_out, out);
}

// Round 6
// 373.024 us; speedup vs baseline: 1.0376x; 1.0153x over previous
//
#include <hip/hip_runtime.h>
#include <stdint.h>

// SNN pipeline, algebraically fused: y2 = x @ (Wh@Wp)^T + (Wh@bp + bh), then
// T-parallel LIF scan (shadowing warm-up), pool+head.
// r9/r10: 256^2 8-wave 4-phase gemm_main, triple-buffer LDS, counted vmcnt,
//   XOR swizzle, one-phase-ahead ds_reads -> 126us, conflicts 0. r11/r12
//   schedule variants FAILED. r13: lif vectorization null -> lif not a cost.
// r14: (a) prep's x->f16 pass (192 MB, ~30us) ELIMINATED: gemm_main reads x
//   f32 directly; A reg-staged (issue loads P0, vmcnt+cvt+swizzled ds_write
//   P3). bnx promote dropped (bh re-read at P3) to hold arch VGPR <=128.
//   (b) gemm_w 4-way K-split (64->256 blocks, full chip) + f32 partials +
//   reduce/split kernel (order diff ~1e-7, invisible at absmax 4.9e-4).

typedef short v8s __attribute__((ext_vector_type(8)));
typedef _Float16 v8h __attribute__((ext_vector_type(8)));
typedef float v4f __attribute__((ext_vector_type(4)));

#define GAS __attribute__((address_space(1)))
#define LAS __attribute__((address_space(3)))
#define SB __builtin_amdgcn_sched_barrier(0)

__device__ __forceinline__ unsigned short f2bf(float f) {
  unsigned int u = __float_as_uint(f);
  u += 0x7fffu + ((u >> 16) & 1u);   // round-to-nearest-even
  return (unsigned short)(u >> 16);
}
__device__ __forceinline__ float bf2f(unsigned short h) {
  return __uint_as_float(((unsigned int)h) << 16);
}
__device__ __forceinline__ unsigned short f2h(float f) {       // f32->f16 RNE
  union { _Float16 h; unsigned short u; } c;
  c.h = (_Float16)f;
  return c.u;
}
__device__ __forceinline__ float h2f(unsigned short u) {
  union { unsigned short u; _Float16 h; } c;
  c.u = u;
  return (float)c.h;
}

__device__ __forceinline__ void gld_lds16(const void* g, void* l) {
  __builtin_amdgcn_global_load_lds((const GAS void*)g, (LAS void*)l, 16, 0, 0);
}

__device__ __forceinline__ v8h cvt8(float4 a, float4 b) {   // RNE, == f2h
  v8h h;
  h[0] = (_Float16)a.x; h[1] = (_Float16)a.y; h[2] = (_Float16)a.z; h[3] = (_Float16)a.w;
  h[4] = (_Float16)b.x; h[5] = (_Float16)b.y; h[6] = (_Float16)b.z; h[7] = (_Float16)b.w;
  return h;
}

__device__ __forceinline__ void split4(const float4 x, ushort4* h, ushort4* l) {
  h->x = f2bf(x.x); l->x = f2bf(x.x - bf2f(h->x));
  h->y = f2bf(x.y); l->y = f2bf(x.y - bf2f(h->y));
  h->z = f2bf(x.z); l->z = f2bf(x.z - bf2f(h->z));
  h->w = f2bf(x.w); l->w = f2bf(x.w - bf2f(h->w));
}

// Weight preprocessing only (x->f16 now fused into gemm_main A-staging):
//  [0, 1024):    transpose+split W_proj -> WpT bf16 hi/lo
//  [1024, 2048): split W_hid -> Wh bf16 hi/lo
//  [2048, 2304): bc[g] = Wh[g,:].b_proj + b_hid[g]  (4 waves/block)
__global__ void __launch_bounds__(256) prep_kernel(
    const float* __restrict__ W_proj, const float* __restrict__ W_hid,
    const float* __restrict__ b_proj, const float* __restrict__ b_hid,
    unsigned short* __restrict__ WpTh, unsigned short* __restrict__ WpTl,
    unsigned short* __restrict__ Whh, unsigned short* __restrict__ Whl,
    float* __restrict__ bc) {
  __shared__ float t[32][33];
  const int blk = blockIdx.x, tid = threadIdx.x;
  if (blk < 1024) {
    const int b2 = blk;
    const int tx = tid & 31, ty = tid >> 5;  // 32x8
    const int bx = b2 & 31, by = b2 >> 5;
    const int xc = bx * 32 + tx;
    const int yb = by * 32;
#pragma unroll
    for (int j = 0; j < 4; ++j) t[ty + 8 * j][tx] = W_proj[(size_t)(yb + ty + 8 * j) * 1024 + xc];
    __syncthreads();
    const int xo = yb + tx;
#pragma unroll
    for (int j = 0; j < 4; ++j) {
      const float v = t[tx][ty + 8 * j];
      const unsigned short h = f2bf(v);
      const size_t o = (size_t)(bx * 32 + ty + 8 * j) * 1024 + xo;
      WpTh[o] = h;
      WpTl[o] = f2bf(v - bf2f(h));
    }
  } else if (blk < 2048) {
    const int i = (blk - 1024) * 256 + tid;  // 262144 float4 = 1M floats
    float4 v = ((const float4*)W_hid)[i];
    ushort4 h, l;
    split4(v, &h, &l);
    ((ushort4*)Whh)[i] = h;
    ((ushort4*)Whl)[i] = l;
  } else {
    const int g = (blk - 2048) * 4 + (tid >> 6);
    const int lane = tid & 63;
    const float* wr = W_hid + (size_t)g * 1024;
    float s = 0.f;
#pragma unroll
    for (int i = 0; i < 16; ++i) s += wr[lane + 64 * i] * b_proj[lane + 64 * i];
#pragma unroll
    for (int off = 32; off > 0; off >>= 1) s += __shfl_down(s, off);
    if (lane == 0) bc[g] = s + b_hid[g];
  }
}

// Weight GEMM, K-split x4: P[ks] = Wh @ WpT^T over K-range [ks*256,ks*256+256),
// bf16 hi/lo 3-product, 128x128 tile, f32 partial out. 256 blocks = full chip.
__global__ void __launch_bounds__(256, 2)
gemm_w(const unsigned short* __restrict__ Ah, const unsigned short* __restrict__ Al,
       const unsigned short* __restrict__ Bh, const unsigned short* __restrict__ Bl,
       float* __restrict__ outP) {
  constexpr int K = 1024, N = 1024;
  __shared__ unsigned short lA[2][128 * 32];
  __shared__ unsigned short lB[2][128 * 32];

  const int tid = threadIdx.x;
  const int ks = blockIdx.x >> 6;
  const int tile = blockIdx.x & 63;
  const int mt = tile & 7, nt = tile >> 3;
  const int m0 = mt * 128, n0 = nt * 128;

  const int lane = tid & 63, wave = tid >> 6;
  const int wm = (wave >> 1) * 64, wn = (wave & 1) * 64;
  const int quad = lane >> 4, r = lane & 15;
  const int srow = tid >> 2, scol = (tid & 3) * 8;

  v4f acc[4][4];
#pragma unroll
  for (int i = 0; i < 4; ++i)
#pragma unroll
    for (int j = 0; j < 4; ++j) acc[i][j] = v4f{0.f, 0.f, 0.f, 0.f};

  const unsigned short* gAh = Ah + (size_t)(m0 + srow) * K + scol;
  const unsigned short* gAl = Al + (size_t)(m0 + srow) * K + scol;
  const unsigned short* gBh = Bh + (size_t)(n0 + srow) * K + scol;
  const unsigned short* gBl = Bl + (size_t)(n0 + srow) * K + scol;

  for (int kt = ks * 256; kt < ks * 256 + 256; kt += 32) {
    gld_lds16(gAh + kt,          &lA[0][tid * 8]);
    gld_lds16(gAh + kt + 64 * K, &lA[0][tid * 8 + 64 * 32]);
    gld_lds16(gAl + kt,          &lA[1][tid * 8]);
    gld_lds16(gAl + kt + 64 * K, &lA[1][tid * 8 + 64 * 32]);
    gld_lds16(gBh + kt,          &lB[0][tid * 8]);
    gld_lds16(gBh + kt + 64 * K, &lB[0][tid * 8 + 64 * 32]);
    gld_lds16(gBl + kt,          &lB[1][tid * 8]);
    gld_lds16(gBl + kt + 64 * K, &lB[1][tid * 8 + 64 * 32]);
    __syncthreads();

    v8s ah[4], al[4], bh[4], bl[4];
#pragma unroll
    for (int i = 0; i < 4; ++i) {
      ah[i] = *(const v8s*)&lA[0][(wm + i * 16 + r) * 32 + quad * 8];
      al[i] = *(const v8s*)&lA[1][(wm + i * 16 + r) * 32 + quad * 8];
      bh[i] = *(const v8s*)&lB[0][(wn + i * 16 + r) * 32 + quad * 8];
      bl[i] = *(const v8s*)&lB[1][(wn + i * 16 + r) * 32 + quad * 8];
    }
#pragma unroll
    for (int i = 0; i < 4; ++i)
#pragma unroll
      for (int j = 0; j < 4; ++j) {
        acc[i][j] = __builtin_amdgcn_mfma_f32_16x16x32_bf16(ah[i], bh[j], acc[i][j], 0, 0, 0);
        acc[i][j] = __builtin_amdgcn_mfma_f32_16x16x32_bf16(ah[i], bl[j], acc[i][j], 0, 0, 0);
        acc[i][j] = __builtin_amdgcn_mfma_f32_16x16x32_bf16(al[i], bh[j], acc[i][j], 0, 0, 0);
      }
    __syncthreads();
  }

  float* op = outP + ((size_t)ks << 20);
#pragma unroll
  for (int i = 0; i < 4; ++i)
#pragma unroll
    for (int j = 0; j < 4; ++j) {
      const int gn = n0 + wn + j * 16 + r;
#pragma unroll
      for (int q2 = 0; q2 < 4; ++q2) {
        const int gm = m0 + wm + i * 16 + quad * 4 + q2;
        op[(size_t)gm * N + gn] = acc[i][j][q2];
      }
    }
}

// Reduce 4 K-slices and split Wc to f16 hi/lo (22 bits).
__global__ void __launch_bounds__(256) wsplit_kernel(const float* __restrict__ P,
                                                     unsigned short* __restrict__ outH,
                                                     unsigned short* __restrict__ outL) {
  const int i = (blockIdx.x * 256 + threadIdx.x) * 4;  // grid 1024 -> 1M elems
  float4 s  = *(const float4*)&P[i];
  const float4 s1 = *(const float4*)&P[i + (1 << 20)];
  const float4 s2 = *(const float4*)&P[i + (2 << 20)];
  const float4 s3 = *(const float4*)&P[i + (3 << 20)];
  s.x += s1.x; s.x += s2.x; s.x += s3.x;
  s.y += s1.y; s.y += s2.y; s.y += s3.y;
  s.z += s1.z; s.z += s2.z; s.z += s3.z;
  s.w += s1.w; s.w += s2.w; s.w += s3.w;
  ushort4 h, l;
  h.x = f2h(s.x); l.x = f2h(s.x - h2f(h.x));
  h.y = f2h(s.y); l.y = f2h(s.y - h2f(h.y));
  h.z = f2h(s.z); l.z = f2h(s.z - h2f(h.z));
  h.w = f2h(s.w); l.w = f2h(s.w - h2f(h.w));
  *(ushort4*)&outH[i] = h;
  *(ushort4*)&outL[i] = l;
}

// Main GEMM: Y2(f16) = x(f32->f16 in-staging) @ Wc^T + bc. 256x256 tile,
// 8 waves (2Mx4N) each 128x64. BK=32, 4 phases x 16 MFMA (r10 skeleton).
// Triple-buffered LDS. A reg-staged from f32 x: issue 4 global_load_dwordx4
// at P0; vmcnt(2)+cvt(RNE)+2 swizzled ds_write_b128 at P3 (T14 split). B
// planes gld_lds-direct (B0@P1, B1@P2) with inverse-swizzled source.
// vmcnt order/iter: A(4)@P0, B0(2)@P1, B1(2)@P2 -> P3 vmcnt(2) leaves only
// this iter's B1. bh re-read at P3 from Bn (replaces bnx promote; keeps
// arch VGPR <=128 so 2 waves/SIMD holds with 128 acc regs).
__global__ void __launch_bounds__(512, 2)
gemm_main(const float* __restrict__ X,
          const unsigned short* __restrict__ Bh, const unsigned short* __restrict__ Bl,
          const float* __restrict__ bias, unsigned short* __restrict__ outH, int M) {
  constexpr int K = 1024, N = 1024;
  __shared__ unsigned short lA[3][8192];   // 48 KB
  __shared__ unsigned short lB0[3][8192];  // 48 KB
  __shared__ unsigned short lB1[3][8192];  // 48 KB

  const int tid = threadIdx.x;
  const int band = (M >> 8) >> 3;            // 16 for M=32768
  const int c = blockIdx.x & 7, idx = blockIdx.x >> 3;   // 512 blocks, %8==0
  const int mt = c * band + (idx >> 2), nt = idx & 3;
  const int m0 = mt * 256, n0 = nt * 256;

  const int lane = tid & 63, wave = tid >> 6;
  const int wm = (wave >> 2) * 128, wn = (wave & 3) * 64;
  const int quad = lane >> 4, r = lane & 15;
  // swizzled read column (shorts): physical slot = quad ^ ((row>>1)&3)
  const int cs = (quad ^ ((r >> 1) & 3)) * 8;
  const int aoff = (wm + r) * 32 + cs;   // + i*512 per fragment
  const int boff = (wn + r) * 32 + cs;   // + j*512 per fragment

  const int srow = tid >> 2;                           // 0..127 (+128)
  const int sslot = (tid & 3) ^ ((tid >> 3) & 3);
  // A: f32 source at LINEAR slot; swizzle applied on the ds_write side
  // (phys slot = (tid&3)^((row>>1)&3) = sslot since row = tid>>2).
  const float* gX = X + (size_t)(m0 + srow) * K + (tid & 3) * 8;
  const int wAo = srow * 32 + sslot * 8;               // f16 units
  // B: gld_lds direct, inverse-swizzled global source, linear LDS dest
  const unsigned short* gB0p = Bh + (size_t)(n0 + srow) * K + sslot * 8;
  const unsigned short* gB1p = Bl + (size_t)(n0 + srow) * K + sslot * 8;

  v4f acc[8][4];
#pragma unroll
  for (int i = 0; i < 8; ++i)
#pragma unroll
    for (int j = 0; j < 4; ++j) acc[i][j] = v4f{0.f, 0.f, 0.f, 0.f};

  unsigned short *Ac = lA[0],  *An = lA[1],  *A2 = lA[2];
  unsigned short *Bc = lB0[0], *Bn = lB0[1], *B2 = lB0[2];
  unsigned short *Cc = lB1[0], *Cn = lB1[1], *C2 = lB1[2];

  // ---- prologue: batches K0 then K1, order pinned by sched_barrier ----
  float4 p00, p01, p02, p03, p10, p11, p12, p13;
  p00 = *(const float4*)(gX);
  p01 = *(const float4*)(gX + 4);
  p02 = *(const float4*)(gX + 128 * K);
  p03 = *(const float4*)(gX + 128 * K + 4);
  SB;
  gld_lds16(gB0p,            &Bc[tid * 8]);
  gld_lds16(gB0p + 128 * K,  &Bc[4096 + tid * 8]);
  gld_lds16(gB1p,            &Cc[tid * 8]);
  gld_lds16(gB1p + 128 * K,  &Cc[4096 + tid * 8]);
  SB;
  p10 = *(const float4*)(gX + 32);
  p11 = *(const float4*)(gX + 36);
  p12 = *(const float4*)(gX + 32 + 128 * K);
  p13 = *(const float4*)(gX + 36 + 128 * K);
  SB;
  gld_lds16(gB0p + 32,           &Bn[tid * 8]);
  gld_lds16(gB0p + 32 + 128 * K, &Bn[4096 + tid * 8]);
  gld_lds16(gB1p + 32,           &Cn[tid * 8]);
  gld_lds16(gB1p + 32 + 128 * K, &Cn[4096 + tid * 8]);
  SB;
  asm volatile("s_waitcnt vmcnt(12)" ::: "memory");  // K0 A done
  SB;
  *(v8h*)&Ac[wAo] = cvt8(p00, p01);
  *(v8h*)&Ac[4096 + wAo] = cvt8(p02, p03);
  SB;
  asm volatile("s_waitcnt vmcnt(2)" ::: "memory");   // K0 B + K1 A,B0 done
  SB;
  *(v8h*)&An[wAo] = cvt8(p10, p11);
  *(v8h*)&An[4096 + wAo] = cvt8(p12, p13);
  asm volatile("s_waitcnt lgkmcnt(0)" ::: "memory");
  __builtin_amdgcn_s_barrier();
  SB;

  v8h ah[4], bh[4];
#pragma unroll
  for (int i = 0; i < 4; ++i) ah[i] = *(const v8h*)&Ac[aoff + i * 512];
#pragma unroll
  for (int j = 0; j < 4; ++j) bh[j] = *(const v8h*)&Bc[boff + j * 512];
  asm volatile("s_waitcnt lgkmcnt(0)" ::: "memory");
  SB;

#pragma unroll 1
  for (int t = 0; t < 32; ++t) {
    const int kp = (t + 2) * 32;
    const bool pf = (t < 30);
    v8h bl[4], ah2[4], anx[4];
    float4 a0, a1, a2, a3;

    // ---- P0: read bl(cur); issue A f32 loads (t+2); MFMA ah x bh ----
#pragma unroll
    for (int j = 0; j < 4; ++j) bl[j] = *(const v8h*)&Cc[boff + j * 512];
    if (pf) {
      a0 = *(const float4*)(gX + kp);
      a1 = *(const float4*)(gX + kp + 4);
      a2 = *(const float4*)(gX + kp + 128 * K);
      a3 = *(const float4*)(gX + kp + 128 * K + 4);
    }
    SB;
    __builtin_amdgcn_s_barrier();
    asm volatile("s_waitcnt lgkmcnt(4)" ::: "memory");  // bh done; bl in flight
    SB;
    __builtin_amdgcn_s_setprio(1);
#pragma unroll
    for (int i = 0; i < 4; ++i)
#pragma unroll
      for (int j = 0; j < 4; ++j)
        acc[i][j] = __builtin_amdgcn_mfma_f32_16x16x32_f16(ah[i], bh[j], acc[i][j], 0, 0, 0);
    __builtin_amdgcn_s_setprio(0);
    SB;
    __builtin_amdgcn_s_barrier();

    // ---- P1: read ah2(cur); stage B0 -> B2; MFMA ah x bl ----
#pragma unroll
    for (int i = 0; i < 4; ++i) ah2[i] = *(const v8h*)&Ac[aoff + (4 + i) * 512];
    if (pf) {
      gld_lds16(gB0p + kp,           &B2[tid * 8]);
      gld_lds16(gB0p + kp + 128 * K, &B2[4096 + tid * 8]);
    }
    SB;
    __builtin_amdgcn_s_barrier();
    asm volatile("s_waitcnt lgkmcnt(4)" ::: "memory");  // bl done; ah2 in flight
    SB;
    __builtin_amdgcn_s_setprio(1);
#pragma unroll
    for (int i = 0; i < 4; ++i)
#pragma unroll
      for (int j = 0; j < 4; ++j)
        acc[i][j] = __builtin_amdgcn_mfma_f32_16x16x32_f16(ah[i], bl[j], acc[i][j], 0, 0, 0);
    __builtin_amdgcn_s_setprio(0);
    SB;
    __builtin_amdgcn_s_barrier();

    // ---- P2: read anx from An; stage B1 -> C2; MFMA ah2 x bh ----
#pragma unroll
    for (int i = 0; i < 4; ++i) anx[i] = *(const v8h*)&An[aoff + i * 512];
    if (pf) {
      gld_lds16(gB1p + kp,           &C2[tid * 8]);
      gld_lds16(gB1p + kp + 128 * K, &C2[4096 + tid * 8]);
    }
    SB;
    __builtin_amdgcn_s_barrier();
    asm volatile("s_waitcnt lgkmcnt(4)" ::: "memory");  // ah2 done; anx in flight
    SB;
    __builtin_amdgcn_s_setprio(1);
#pragma unroll
    for (int i = 0; i < 4; ++i)
#pragma unroll
      for (int j = 0; j < 4; ++j)
        acc[4 + i][j] = __builtin_amdgcn_mfma_f32_16x16x32_f16(ah2[i], bh[j], acc[4 + i][j], 0, 0, 0);
    __builtin_amdgcn_s_setprio(0);
    SB;
    __builtin_amdgcn_s_barrier();

    // ---- P3: MFMA ah2 x bl; then A cvt+write; publish; read next bh ----
    __builtin_amdgcn_s_setprio(1);
#pragma unroll
    for (int i = 0; i < 4; ++i)
#pragma unroll
      for (int j = 0; j < 4; ++j)
        acc[4 + i][j] = __builtin_amdgcn_mfma_f32_16x16x32_f16(ah2[i], bl[j], acc[4 + i][j], 0, 0, 0);
    __builtin_amdgcn_s_setprio(0);
    SB;
    if (pf) {
      // outstanding vm: prev B1(2) + A(4) + B0(2) + B1(2) = 10 -> drain to 2:
      // A loads done for cvt; buffer nxt fully confirmed; this B1 in flight.
      asm volatile("s_waitcnt vmcnt(2)" ::: "memory");
      SB;
      *(v8h*)&A2[wAo] = cvt8(a0, a1);
      *(v8h*)&A2[4096 + wAo] = cvt8(a2, a3);
    } else {
      asm volatile("s_waitcnt vmcnt(0)" ::: "memory");
    }
    asm volatile("s_waitcnt lgkmcnt(0)" ::: "memory");  // publish A; anx drained
    SB;
#pragma unroll
    for (int j = 0; j < 4; ++j) bh[j] = *(const v8h*)&Bn[boff + j * 512];  // next iter
    SB;
    __builtin_amdgcn_s_barrier();
    SB;

    // promote A fragments; rotate buffers
#pragma unroll
    for (int i = 0; i < 4; ++i) ah[i] = anx[i];
    unsigned short* tp;
    tp = Ac; Ac = An; An = A2; A2 = tp;
    tp = Bc; Bc = Bn; Bn = B2; B2 = tp;
    tp = Cc; Cc = Cn; Cn = C2; C2 = tp;
  }

  // epilogue: C[m = quad*4+q2][n = lane&15]; store f16 with bias
  float bv[4];
#pragma unroll
  for (int j = 0; j < 4; ++j) bv[j] = bias[n0 + wn + j * 16 + r];
#pragma unroll
  for (int i = 0; i < 8; ++i)
#pragma unroll
    for (int j = 0; j < 4; ++j) {
      const int gn = n0 + wn + j * 16 + r;
#pragma unroll
      for (int q2 = 0; q2 < 4; ++q2) {
        const int gm = m0 + wm + i * 16 + quad * 4 + q2;
        outH[(size_t)gm * N + gn] = f2h(acc[i][j][q2] + bv[j]);
      }
    }
}

// T-parallel LIF over f16 y2: 8 chunks of 128 steps, 32-step shadowing
// warm-up. 4 channels/thread, ushort4 loads.
__global__ void __launch_bounds__(256) lif_part_kernel(const unsigned short* __restrict__ y2,
                                                       float* __restrict__ part) {
  const int gid = blockIdx.x * 256 + threadIdx.x;   // 65536 threads
  const int chunk = gid >> 13;                      // 8192 threads/chunk
  const int c4 = (gid & 8191) << 2;                 // base channel, %4==0
  const unsigned short* p = y2 + ((size_t)(c4 >> 10) << 20) + (c4 & 1023);
  const int t0 = chunk << 7;
  float v0 = 0.f, v1 = 0.f, v2 = 0.f, v3 = 0.f;
  if (chunk) {  // uniform per wave (8192 % 64 == 0)
    const unsigned short* pw = p + (size_t)(t0 - 32) * 1024;
    for (int b = 0; b < 32; b += 16) {
      ushort4 x[16];
#pragma unroll
      for (int i = 0; i < 16; ++i) x[i] = *(const ushort4*)&pw[(size_t)(b + i) * 1024];
#pragma unroll
      for (int i = 0; i < 16; ++i) {
        v0 += (h2f(x[i].x) - v0) * 0.5f; if (v0 >= 1.0f) v0 -= 1.0f;
        v1 += (h2f(x[i].y) - v1) * 0.5f; if (v1 >= 1.0f) v1 -= 1.0f;
        v2 += (h2f(x[i].z) - v2) * 0.5f; if (v2 >= 1.0f) v2 -= 1.0f;
        v3 += (h2f(x[i].w) - v3) * 0.5f; if (v3 >= 1.0f) v3 -= 1.0f;
      }
    }
  }
  float c0 = 0.f, c1 = 0.f, c2 = 0.f, c3 = 0.f;
  const unsigned short* pm = p + (size_t)t0 * 1024;
  for (int b = 0; b < 128; b += 16) {
    ushort4 x[16];
#pragma unroll
    for (int i = 0; i < 16; ++i) x[i] = *(const ushort4*)&pm[(size_t)(b + i) * 1024];
#pragma unroll
    for (int i = 0; i < 16; ++i) {
      float s;
      v0 += (h2f(x[i].x) - v0) * 0.5f; s = (v0 >= 1.0f) ? 1.0f : 0.0f; c0 += s; v0 -= s;
      v1 += (h2f(x[i].y) - v1) * 0.5f; s = (v1 >= 1.0f) ? 1.0f : 0.0f; c1 += s; v1 -= s;
      v2 += (h2f(x[i].z) - v2) * 0.5f; s = (v2 >= 1.0f) ? 1.0f : 0.0f; c2 += s; v2 -= s;
      v3 += (h2f(x[i].w) - v3) * 0.5f; s = (v3 >= 1.0f) ? 1.0f : 0.0f; c3 += s; v3 -= s;
    }
  }
  float4 o; o.x = c0; o.y = c1; o.z = c2; o.w = c3;
  *(float4*)&part[(size_t)chunk * 32768 + c4] = o;
}

// out[b,o] = (sum_c part[c][b,:]).W_out[o,:]/1024 + b_out[o]; one wave each.
__global__ void __launch_bounds__(64) head_kernel(const float* __restrict__ part,
                                                  const float* __restrict__ W_out,
                                                  const float* __restrict__ b_out,
                                                  float* __restrict__ out) {
  int blk = blockIdx.x;          // 0..319
  int b = blk / 10, o = blk % 10;
  int lane = threadIdx.x;
  const float* wr = W_out + o * 1024;
  float s = 0.f;
#pragma unroll
  for (int i = 0; i < 16; ++i) {
    const int ch = b * 1024 + lane + 64 * i;
    float p = 0.f;
#pragma unroll
    for (int c = 0; c < 8; ++c) p += part[c * 32768 + ch];
    s += p * wr[lane + 64 * i];
  }
#pragma unroll
  for (int off = 32; off > 0; off >>= 1) s += __shfl_down(s, off);
  if (lane == 0) out[b * 10 + o] = s * (1.0f / 1024.0f) + b_out[o];
}

extern "C" void kernel_launch(void* const* d_in, const int* in_sizes, int n_in,
                              void* d_out, int out_size, void* d_ws, size_t ws_size,
                              hipStream_t stream) {
  const float* x      = (const float*)d_in[0];
  const float* W_proj = (const float*)d_in[1];
  const float* b_proj = (const float*)d_in[2];
  const float* W_hid  = (const float*)d_in[3];
  const float* b_hid  = (const float*)d_in[4];
  const float* W_out  = (const float*)d_in[5];
  const float* b_out  = (const float*)d_in[6];
  float* out = (float*)d_out;

  const int M = 32768;  // B*T

  // Workspace: Pws f32 [16MB] (was Xh) | Y2 f16 [64M] | weights | bc | part
  char* ws = (char*)d_ws;
  float*          Pws  = (float*)(ws);
  unsigned short* Y2   = (unsigned short*)(ws + 67108864);
  char* base = ws + 134217728;
  unsigned short* WpTh = (unsigned short*)(base);             // bf16
  unsigned short* WpTl = (unsigned short*)(base + 2097152);
  unsigned short* Whh  = (unsigned short*)(base + 4194304);
  unsigned short* Whl  = (unsigned short*)(base + 6291456);
  unsigned short* Wch  = (unsigned short*)(base + 8388608);   // f16
  unsigned short* Wcl  = (unsigned short*)(base + 10485760);
  float*           bc  = (float*)(base + 12582912);
  float*          part = (float*)(base + 12582912 + 65536);

  prep_kernel<<<2304, 256, 0, stream>>>(W_proj, W_hid, b_proj, b_hid,
                                        WpTh, WpTl, Whh, Whl, bc);
  gemm_w<<<256, 256, 0, stream>>>(Whh, Whl, WpTh, WpTl, Pws);
  wsplit_kernel<<<1024, 256, 0, stream>>>(Pws, Wch, Wcl);
  gemm_main<<<512, 512, 0, stream>>>(x, Wch, Wcl, bc, Y2, M);
  lif_part_kernel<<<256, 256, 0, stream>>>(Y2, part);
  head_kernel<<<320, 64, 0, stream>>>(part, W_out, b_out, out);
}

// Round 7
// 358.101 us; speedup vs baseline: 1.0808x; 1.0417x over previous
//
#include <hip/hip_runtime.h>
#include <stdint.h>

// SNN pipeline, algebraically fused: y2 = x @ (Wh@Wp)^T + (Wh@bp + bh), then
// T-parallel LIF scan (shadowing warm-up), pool+head.
// r10: 256^2 8-wave 4-phase gemm_main, triple-buffer LDS, counted vmcnt,
//   XOR swizzle, one-phase-ahead ds_reads -> 126us, conflicts 0 (reproduced
//   3x). r11/r12 schedule variants FAILED. r14: x->f16 fused into A-staging
//   REGRESSED gemm_main 126->194 (serial P3 tail + 2x A bytes) but gemm_w
//   K-split + weights-only prep saved 73us hidden. r15: unbundle -- keep
//   K-split gemm_w + wsplit, revert gemm_main to r10-exact (f16 Xh input),
//   standalone x->f16 streaming pass (~30us, cheaper than the 68us fusion
//   cost). Pws aliases Y2 (consumed by wsplit before gemm_main writes Y2).

typedef short v8s __attribute__((ext_vector_type(8)));
typedef _Float16 v8h __attribute__((ext_vector_type(8)));
typedef float v4f __attribute__((ext_vector_type(4)));

#define GAS __attribute__((address_space(1)))
#define LAS __attribute__((address_space(3)))

__device__ __forceinline__ unsigned short f2bf(float f) {
  unsigned int u = __float_as_uint(f);
  u += 0x7fffu + ((u >> 16) & 1u);   // round-to-nearest-even
  return (unsigned short)(u >> 16);
}
__device__ __forceinline__ float bf2f(unsigned short h) {
  return __uint_as_float(((unsigned int)h) << 16);
}
__device__ __forceinline__ unsigned short f2h(float f) {       // f32->f16 RNE
  union { _Float16 h; unsigned short u; } c;
  c.h = (_Float16)f;
  return c.u;
}
__device__ __forceinline__ float h2f(unsigned short u) {
  union { unsigned short u; _Float16 h; } c;
  c.u = u;
  return (float)c.h;
}

__device__ __forceinline__ void gld_lds16(const void* g, void* l) {
  __builtin_amdgcn_global_load_lds((const GAS void*)g, (LAS void*)l, 16, 0, 0);
}

__device__ __forceinline__ void split4(const float4 x, ushort4* h, ushort4* l) {
  h->x = f2bf(x.x); l->x = f2bf(x.x - bf2f(h->x));
  h->y = f2bf(x.y); l->y = f2bf(x.y - bf2f(h->y));
  h->z = f2bf(x.z); l->z = f2bf(x.z - bf2f(h->z));
  h->w = f2bf(x.w); l->w = f2bf(x.w - bf2f(h->w));
}

// Fused preprocessing (one launch, independent block ranges):
//  [0, 32768):      x -> f16 plane Xh           (192 MB traffic, HBM-bound)
//  [32768, 33792):  transpose+split W_proj -> WpT bf16 hi/lo
//  [33792, 34816):  split W_hid -> Wh bf16 hi/lo
//  [34816, 35072):  bc[g] = Wh[g,:].b_proj + b_hid[g]  (4 waves/block)
__global__ void __launch_bounds__(256) prep_kernel(
    const float* __restrict__ x,
    const float* __restrict__ W_proj, const float* __restrict__ W_hid,
    const float* __restrict__ b_proj, const float* __restrict__ b_hid,
    unsigned short* __restrict__ Xh,
    unsigned short* __restrict__ WpTh, unsigned short* __restrict__ WpTl,
    unsigned short* __restrict__ Whh, unsigned short* __restrict__ Whl,
    float* __restrict__ bc) {
  __shared__ float t[32][33];
  const int blk = blockIdx.x, tid = threadIdx.x;
  if (blk < 32768) {
    const int i = blk * 256 + tid;           // 8388608 float4 = 32M floats
    float4 v = ((const float4*)x)[i];
    ushort4 h;
    h.x = f2h(v.x); h.y = f2h(v.y); h.z = f2h(v.z); h.w = f2h(v.w);
    ((ushort4*)Xh)[i] = h;
  } else if (blk < 33792) {
    const int b2 = blk - 32768;
    const int tx = tid & 31, ty = tid >> 5;  // 32x8
    const int bx = b2 & 31, by = b2 >> 5;
    const int xc = bx * 32 + tx;
    const int yb = by * 32;
#pragma unroll
    for (int j = 0; j < 4; ++j) t[ty + 8 * j][tx] = W_proj[(size_t)(yb + ty + 8 * j) * 1024 + xc];
    __syncthreads();
    const int xo = yb + tx;
#pragma unroll
    for (int j = 0; j < 4; ++j) {
      const float v = t[tx][ty + 8 * j];
      const unsigned short h = f2bf(v);
      const size_t o = (size_t)(bx * 32 + ty + 8 * j) * 1024 + xo;
      WpTh[o] = h;
      WpTl[o] = f2bf(v - bf2f(h));
    }
  } else if (blk < 34816) {
    const int i = (blk - 33792) * 256 + tid; // 262144 float4 = 1M floats
    float4 v = ((const float4*)W_hid)[i];
    ushort4 h, l;
    split4(v, &h, &l);
    ((ushort4*)Whh)[i] = h;
    ((ushort4*)Whl)[i] = l;
  } else {
    const int g = (blk - 34816) * 4 + (tid >> 6);
    const int lane = tid & 63;
    const float* wr = W_hid + (size_t)g * 1024;
    float s = 0.f;
#pragma unroll
    for (int i = 0; i < 16; ++i) s += wr[lane + 64 * i] * b_proj[lane + 64 * i];
#pragma unroll
    for (int off = 32; off > 0; off >>= 1) s += __shfl_down(s, off);
    if (lane == 0) bc[g] = s + b_hid[g];
  }
}

// Weight GEMM, K-split x4: P[ks] = Wh @ WpT^T over K-range [ks*256,ks*256+256),
// bf16 hi/lo 3-product, 128x128 tile, f32 partial out. 256 blocks = full chip.
__global__ void __launch_bounds__(256, 2)
gemm_w(const unsigned short* __restrict__ Ah, const unsigned short* __restrict__ Al,
       const unsigned short* __restrict__ Bh, const unsigned short* __restrict__ Bl,
       float* __restrict__ outP) {
  constexpr int K = 1024, N = 1024;
  __shared__ unsigned short lA[2][128 * 32];
  __shared__ unsigned short lB[2][128 * 32];

  const int tid = threadIdx.x;
  const int ks = blockIdx.x >> 6;
  const int tile = blockIdx.x & 63;
  const int mt = tile & 7, nt = tile >> 3;
  const int m0 = mt * 128, n0 = nt * 128;

  const int lane = tid & 63, wave = tid >> 6;
  const int wm = (wave >> 1) * 64, wn = (wave & 1) * 64;
  const int quad = lane >> 4, r = lane & 15;
  const int srow = tid >> 2, scol = (tid & 3) * 8;

  v4f acc[4][4];
#pragma unroll
  for (int i = 0; i < 4; ++i)
#pragma unroll
    for (int j = 0; j < 4; ++j) acc[i][j] = v4f{0.f, 0.f, 0.f, 0.f};

  const unsigned short* gAh = Ah + (size_t)(m0 + srow) * K + scol;
  const unsigned short* gAl = Al + (size_t)(m0 + srow) * K + scol;
  const unsigned short* gBh = Bh + (size_t)(n0 + srow) * K + scol;
  const unsigned short* gBl = Bl + (size_t)(n0 + srow) * K + scol;

  for (int kt = ks * 256; kt < ks * 256 + 256; kt += 32) {
    gld_lds16(gAh + kt,          &lA[0][tid * 8]);
    gld_lds16(gAh + kt + 64 * K, &lA[0][tid * 8 + 64 * 32]);
    gld_lds16(gAl + kt,          &lA[1][tid * 8]);
    gld_lds16(gAl + kt + 64 * K, &lA[1][tid * 8 + 64 * 32]);
    gld_lds16(gBh + kt,          &lB[0][tid * 8]);
    gld_lds16(gBh + kt + 64 * K, &lB[0][tid * 8 + 64 * 32]);
    gld_lds16(gBl + kt,          &lB[1][tid * 8]);
    gld_lds16(gBl + kt + 64 * K, &lB[1][tid * 8 + 64 * 32]);
    __syncthreads();

    v8s ah[4], al[4], bh[4], bl[4];
#pragma unroll
    for (int i = 0; i < 4; ++i) {
      ah[i] = *(const v8s*)&lA[0][(wm + i * 16 + r) * 32 + quad * 8];
      al[i] = *(const v8s*)&lA[1][(wm + i * 16 + r) * 32 + quad * 8];
      bh[i] = *(const v8s*)&lB[0][(wn + i * 16 + r) * 32 + quad * 8];
      bl[i] = *(const v8s*)&lB[1][(wn + i * 16 + r) * 32 + quad * 8];
    }
#pragma unroll
    for (int i = 0; i < 4; ++i)
#pragma unroll
      for (int j = 0; j < 4; ++j) {
        acc[i][j] = __builtin_amdgcn_mfma_f32_16x16x32_bf16(ah[i], bh[j], acc[i][j], 0, 0, 0);
        acc[i][j] = __builtin_amdgcn_mfma_f32_16x16x32_bf16(ah[i], bl[j], acc[i][j], 0, 0, 0);
        acc[i][j] = __builtin_amdgcn_mfma_f32_16x16x32_bf16(al[i], bh[j], acc[i][j], 0, 0, 0);
      }
    __syncthreads();
  }

  float* op = outP + ((size_t)ks << 20);
#pragma unroll
  for (int i = 0; i < 4; ++i)
#pragma unroll
    for (int j = 0; j < 4; ++j) {
      const int gn = n0 + wn + j * 16 + r;
#pragma unroll
      for (int q2 = 0; q2 < 4; ++q2) {
        const int gm = m0 + wm + i * 16 + quad * 4 + q2;
        op[(size_t)gm * N + gn] = acc[i][j][q2];
      }
    }
}

// Reduce 4 K-slices and split Wc to f16 hi/lo (22 bits).
__global__ void __launch_bounds__(256) wsplit_kernel(const float* __restrict__ P,
                                                     unsigned short* __restrict__ outH,
                                                     unsigned short* __restrict__ outL) {
  const int i = (blockIdx.x * 256 + threadIdx.x) * 4;  // grid 1024 -> 1M elems
  float4 s  = *(const float4*)&P[i];
  const float4 s1 = *(const float4*)&P[i + (1 << 20)];
  const float4 s2 = *(const float4*)&P[i + (2 << 20)];
  const float4 s3 = *(const float4*)&P[i + (3 << 20)];
  s.x += s1.x; s.x += s2.x; s.x += s3.x;
  s.y += s1.y; s.y += s2.y; s.y += s3.y;
  s.z += s1.z; s.z += s2.z; s.z += s3.z;
  s.w += s1.w; s.w += s2.w; s.w += s3.w;
  ushort4 h, l;
  h.x = f2h(s.x); l.x = f2h(s.x - h2f(h.x));
  h.y = f2h(s.y); l.y = f2h(s.y - h2f(h.y));
  h.z = f2h(s.z); l.z = f2h(s.z - h2f(h.z));
  h.w = f2h(s.w); l.w = f2h(s.w - h2f(h.w));
  *(ushort4*)&outH[i] = h;
  *(ushort4*)&outL[i] = l;
}

// Main GEMM: Y2(f16) = Xf16 @ Wc^T + bc. 256x256 tile, 8 waves (2Mx4N) each
// owning 128x64. BK=32, both B planes per K-step -> 64 MFMA/wave/K-step split
// into 4 phases x 16 MFMA. Triple-buffered LDS (3 x 48KB). ds_reads issued
// ONE PHASE AHEAD of their MFMA use, with counted lgkmcnt(N). Counted
// vmcnt(4) at P1 confirms buffer nxt one phase before P2's cross-K-step
// prefetch reads it. Bank swizzle via pre-swizzled global source + swizzled
// ds_read addr (rule #21). [r10-exact: 126us / MfmaUtil 47 / conflicts 0,
// reproduced 3x; r11/r12/r14 variants all regressed -- do not modify.]
__global__ void __launch_bounds__(512, 2)
gemm_main(const unsigned short* __restrict__ Ah,
          const unsigned short* __restrict__ Bh, const unsigned short* __restrict__ Bl,
          const float* __restrict__ bias, unsigned short* __restrict__ outH, int M) {
  constexpr int K = 1024, N = 1024;
  __shared__ unsigned short lA[3][8192];   // 48 KB
  __shared__ unsigned short lB0[3][8192];  // 48 KB
  __shared__ unsigned short lB1[3][8192];  // 48 KB

  const int tid = threadIdx.x;
  const int band = (M >> 8) >> 3;            // 16 for M=32768
  const int c = blockIdx.x & 7, idx = blockIdx.x >> 3;   // 512 blocks, %8==0
  const int mt = c * band + (idx >> 2), nt = idx & 3;
  const int m0 = mt * 256, n0 = nt * 256;

  const int lane = tid & 63, wave = tid >> 6;
  const int wm = (wave >> 2) * 128, wn = (wave & 3) * 64;
  const int quad = lane >> 4, r = lane & 15;
  // swizzled read column (shorts): physical slot = quad ^ ((row>>1)&3)
  const int cs = (quad ^ ((r >> 1) & 3)) * 8;
  const int aoff = (wm + r) * 32 + cs;   // + i*512 per fragment
  const int boff = (wn + r) * 32 + cs;   // + j*512 per fragment

  // staging: thread t -> tile row t>>2, linear LDS slot t&3; global source
  // slot inverse-swizzled so the LDS image is the swizzled layout.
  const int srow = tid >> 2;                           // 0..127 (+128 call 1)
  const int sslot = (tid & 3) ^ ((tid >> 3) & 3);      // same for row+128

  const unsigned short* gA   = Ah + (size_t)(m0 + srow) * K + sslot * 8;
  const unsigned short* gB0p = Bh + (size_t)(n0 + srow) * K + sslot * 8;
  const unsigned short* gB1p = Bl + (size_t)(n0 + srow) * K + sslot * 8;

  v4f acc[8][4];
#pragma unroll
  for (int i = 0; i < 8; ++i)
#pragma unroll
    for (int j = 0; j < 4; ++j) acc[i][j] = v4f{0.f, 0.f, 0.f, 0.f};

  // buffer rotation pointers: cur / nxt / nx2 (staging target)
  unsigned short *Ac = lA[0],  *An = lA[1],  *A2 = lA[2];
  unsigned short *Bc = lB0[0], *Bn = lB0[1], *B2 = lB0[2];
  unsigned short *Cc = lB1[0], *Cn = lB1[1], *C2 = lB1[2];

  // prologue: stage K-step 0 -> buf0, K-step 1 -> buf1 (6 loads each)
  gld_lds16(gA,              &Ac[tid * 8]);
  gld_lds16(gA + 128 * K,    &Ac[4096 + tid * 8]);
  gld_lds16(gB0p,            &Bc[tid * 8]);
  gld_lds16(gB0p + 128 * K,  &Bc[4096 + tid * 8]);
  gld_lds16(gB1p,            &Cc[tid * 8]);
  gld_lds16(gB1p + 128 * K,  &Cc[4096 + tid * 8]);
  gld_lds16(gA + 32,             &An[tid * 8]);
  gld_lds16(gA + 32 + 128 * K,   &An[4096 + tid * 8]);
  gld_lds16(gB0p + 32,           &Bn[tid * 8]);
  gld_lds16(gB0p + 32 + 128 * K, &Bn[4096 + tid * 8]);
  gld_lds16(gB1p + 32,           &Cn[tid * 8]);
  gld_lds16(gB1p + 32 + 128 * K, &Cn[4096 + tid * 8]);
  asm volatile("s_waitcnt vmcnt(6)" ::: "memory");   // buf0 complete
  __builtin_amdgcn_s_barrier();
  __builtin_amdgcn_sched_barrier(0);

  // preload P0 operands of K-step 0 from buf0
  v8h ah[4], bh[4];
#pragma unroll
  for (int i = 0; i < 4; ++i) ah[i] = *(const v8h*)&Ac[aoff + i * 512];
#pragma unroll
  for (int j = 0; j < 4; ++j) bh[j] = *(const v8h*)&Bc[boff + j * 512];
  __builtin_amdgcn_sched_barrier(0);

#pragma unroll 1
  for (int t = 0; t < 32; ++t) {
    const int kp = (t + 2) * 32;
    const bool pf = (t < 30);
    v8h bl[4], ah2[4], anx[4], bnx[4];

    // ---- P0: read bl(cur); stage A -> nx2; MFMA ah x bh ----
#pragma unroll
    for (int j = 0; j < 4; ++j) bl[j] = *(const v8h*)&Cc[boff + j * 512];
    if (pf) {
      gld_lds16(gA + kp,           &A2[tid * 8]);
      gld_lds16(gA + kp + 128 * K, &A2[4096 + tid * 8]);
    }
    __builtin_amdgcn_sched_barrier(0);
    __builtin_amdgcn_s_barrier();
    asm volatile("s_waitcnt lgkmcnt(4)" ::: "memory");  // ah,bh ready; bl in flight
    __builtin_amdgcn_sched_barrier(0);
    __builtin_amdgcn_s_setprio(1);
#pragma unroll
    for (int i = 0; i < 4; ++i)
#pragma unroll
      for (int j = 0; j < 4; ++j)
        acc[i][j] = __builtin_amdgcn_mfma_f32_16x16x32_f16(ah[i], bh[j], acc[i][j], 0, 0, 0);
    __builtin_amdgcn_s_setprio(0);
    __builtin_amdgcn_sched_barrier(0);
    __builtin_amdgcn_s_barrier();

    // ---- P1: read ah2(cur); stage B0 -> nx2; MFMA ah x bl ----
#pragma unroll
    for (int i = 0; i < 4; ++i) ah2[i] = *(const v8h*)&Ac[aoff + (4 + i) * 512];
    if (pf) {
      gld_lds16(gB0p + kp,           &B2[tid * 8]);
      gld_lds16(gB0p + kp + 128 * K, &B2[4096 + tid * 8]);
    }
    __builtin_amdgcn_sched_barrier(0);
    __builtin_amdgcn_s_barrier();
    // vmcnt(4): the 4 newest are this iter's A+B0 stages; everything older
    // (buffer nxt's 6 loads) confirmed -> P2 may read buf nxt after barrier.
    asm volatile("s_waitcnt vmcnt(4) lgkmcnt(4)" ::: "memory");  // bl ready
    __builtin_amdgcn_sched_barrier(0);
    __builtin_amdgcn_s_setprio(1);
#pragma unroll
    for (int i = 0; i < 4; ++i)
#pragma unroll
      for (int j = 0; j < 4; ++j)
        acc[i][j] = __builtin_amdgcn_mfma_f32_16x16x32_f16(ah[i], bl[j], acc[i][j], 0, 0, 0);
    __builtin_amdgcn_s_setprio(0);
    __builtin_amdgcn_sched_barrier(0);
    __builtin_amdgcn_s_barrier();

    // ---- P2: read next K-step's ah,bh from buf nxt; stage B1 -> nx2;
    //          MFMA ah2 x bh ----
#pragma unroll
    for (int i = 0; i < 4; ++i) anx[i] = *(const v8h*)&An[aoff + i * 512];
#pragma unroll
    for (int j = 0; j < 4; ++j) bnx[j] = *(const v8h*)&Bn[boff + j * 512];
    if (pf) {
      gld_lds16(gB1p + kp,           &C2[tid * 8]);
      gld_lds16(gB1p + kp + 128 * K, &C2[4096 + tid * 8]);
    }
    __builtin_amdgcn_sched_barrier(0);
    __builtin_amdgcn_s_barrier();
    asm volatile("s_waitcnt lgkmcnt(8)" ::: "memory");  // ah2 ready; anx,bnx in flight
    __builtin_amdgcn_sched_barrier(0);
    __builtin_amdgcn_s_setprio(1);
#pragma unroll
    for (int i = 0; i < 4; ++i)
#pragma unroll
      for (int j = 0; j < 4; ++j)
        acc[4 + i][j] = __builtin_amdgcn_mfma_f32_16x16x32_f16(ah2[i], bh[j], acc[4 + i][j], 0, 0, 0);
    __builtin_amdgcn_s_setprio(0);
    __builtin_amdgcn_sched_barrier(0);
    __builtin_amdgcn_s_barrier();

    // ---- P3: MFMA ah2 x bl (all operands confirmed earlier) ----
    __builtin_amdgcn_s_setprio(1);
#pragma unroll
    for (int i = 0; i < 4; ++i)
#pragma unroll
      for (int j = 0; j < 4; ++j)
        acc[4 + i][j] = __builtin_amdgcn_mfma_f32_16x16x32_f16(ah2[i], bl[j], acc[4 + i][j], 0, 0, 0);
    __builtin_amdgcn_s_setprio(0);
    __builtin_amdgcn_sched_barrier(0);
    __builtin_amdgcn_s_barrier();

    // rotate buffers; promote prefetched operands
    unsigned short* tp;
    tp = Ac; Ac = An; An = A2; A2 = tp;
    tp = Bc; Bc = Bn; Bn = B2; B2 = tp;
    tp = Cc; Cc = Cn; Cn = C2; C2 = tp;
#pragma unroll
    for (int i = 0; i < 4; ++i) { ah[i] = anx[i]; bh[i] = bnx[i]; }
  }

  // epilogue: C[m = quad*4+q2][n = lane&15]; store f16 with bias
  float bv[4];
#pragma unroll
  for (int j = 0; j < 4; ++j) bv[j] = bias[n0 + wn + j * 16 + r];
#pragma unroll
  for (int i = 0; i < 8; ++i)
#pragma unroll
    for (int j = 0; j < 4; ++j) {
      const int gn = n0 + wn + j * 16 + r;
#pragma unroll
      for (int q2 = 0; q2 < 4; ++q2) {
        const int gm = m0 + wm + i * 16 + quad * 4 + q2;
        outH[(size_t)gm * N + gn] = f2h(acc[i][j][q2] + bv[j]);
      }
    }
}

// T-parallel LIF over f16 y2: 8 chunks of 128 steps, 32-step shadowing
// warm-up. 4 channels/thread, ushort4 loads.
__global__ void __launch_bounds__(256) lif_part_kernel(const unsigned short* __restrict__ y2,
                                                       float* __restrict__ part) {
  const int gid = blockIdx.x * 256 + threadIdx.x;   // 65536 threads
  const int chunk = gid >> 13;                      // 8192 threads/chunk
  const int c4 = (gid & 8191) << 2;                 // base channel, %4==0
  const unsigned short* p = y2 + ((size_t)(c4 >> 10) << 20) + (c4 & 1023);
  const int t0 = chunk << 7;
  float v0 = 0.f, v1 = 0.f, v2 = 0.f, v3 = 0.f;
  if (chunk) {  // uniform per wave (8192 % 64 == 0)
    const unsigned short* pw = p + (size_t)(t0 - 32) * 1024;
    for (int b = 0; b < 32; b += 16) {
      ushort4 x[16];
#pragma unroll
      for (int i = 0; i < 16; ++i) x[i] = *(const ushort4*)&pw[(size_t)(b + i) * 1024];
#pragma unroll
      for (int i = 0; i < 16; ++i) {
        v0 += (h2f(x[i].x) - v0) * 0.5f; if (v0 >= 1.0f) v0 -= 1.0f;
        v1 += (h2f(x[i].y) - v1) * 0.5f; if (v1 >= 1.0f) v1 -= 1.0f;
        v2 += (h2f(x[i].z) - v2) * 0.5f; if (v2 >= 1.0f) v2 -= 1.0f;
        v3 += (h2f(x[i].w) - v3) * 0.5f; if (v3 >= 1.0f) v3 -= 1.0f;
      }
    }
  }
  float c0 = 0.f, c1 = 0.f, c2 = 0.f, c3 = 0.f;
  const unsigned short* pm = p + (size_t)t0 * 1024;
  for (int b = 0; b < 128; b += 16) {
    ushort4 x[16];
#pragma unroll
    for (int i = 0; i < 16; ++i) x[i] = *(const ushort4*)&pm[(size_t)(b + i) * 1024];
#pragma unroll
    for (int i = 0; i < 16; ++i) {
      float s;
      v0 += (h2f(x[i].x) - v0) * 0.5f; s = (v0 >= 1.0f) ? 1.0f : 0.0f; c0 += s; v0 -= s;
      v1 += (h2f(x[i].y) - v1) * 0.5f; s = (v1 >= 1.0f) ? 1.0f : 0.0f; c1 += s; v1 -= s;
      v2 += (h2f(x[i].z) - v2) * 0.5f; s = (v2 >= 1.0f) ? 1.0f : 0.0f; c2 += s; v2 -= s;
      v3 += (h2f(x[i].w) - v3) * 0.5f; s = (v3 >= 1.0f) ? 1.0f : 0.0f; c3 += s; v3 -= s;
    }
  }
  float4 o; o.x = c0; o.y = c1; o.z = c2; o.w = c3;
  *(float4*)&part[(size_t)chunk * 32768 + c4] = o;
}

// out[b,o] = (sum_c part[c][b,:]).W_out[o,:]/1024 + b_out[o]; one wave each.
__global__ void __launch_bounds__(64) head_kernel(const float* __restrict__ part,
                                                  const float* __restrict__ W_out,
                                                  const float* __restrict__ b_out,
                                                  float* __restrict__ out) {
  int blk = blockIdx.x;          // 0..319
  int b = blk / 10, o = blk % 10;
  int lane = threadIdx.x;
  const float* wr = W_out + o * 1024;
  float s = 0.f;
#pragma unroll
  for (int i = 0; i < 16; ++i) {
    const int ch = b * 1024 + lane + 64 * i;
    float p = 0.f;
#pragma unroll
    for (int c = 0; c < 8; ++c) p += part[c * 32768 + ch];
    s += p * wr[lane + 64 * i];
  }
#pragma unroll
  for (int off = 32; off > 0; off >>= 1) s += __shfl_down(s, off);
  if (lane == 0) out[b * 10 + o] = s * (1.0f / 1024.0f) + b_out[o];
}

extern "C" void kernel_launch(void* const* d_in, const int* in_sizes, int n_in,
                              void* d_out, int out_size, void* d_ws, size_t ws_size,
                              hipStream_t stream) {
  const float* x      = (const float*)d_in[0];
  const float* W_proj = (const float*)d_in[1];
  const float* b_proj = (const float*)d_in[2];
  const float* W_hid  = (const float*)d_in[3];
  const float* b_hid  = (const float*)d_in[4];
  const float* W_out  = (const float*)d_in[5];
  const float* b_out  = (const float*)d_in[6];
  float* out = (float*)d_out;

  const int M = 32768;  // B*T

  // Workspace (~143 MB): Xh f16 [64M] | Y2 f16 [64M] | weights | bc | part
  // Pws (16MB gemm_w partials) ALIASES Y2: consumed by wsplit before
  // gemm_main writes Y2 (same stream, ordered).
  char* ws = (char*)d_ws;
  unsigned short* Xh   = (unsigned short*)(ws);
  unsigned short* Y2   = (unsigned short*)(ws + 67108864);
  float*          Pws  = (float*)(ws + 67108864);
  char* base = ws + 134217728;
  unsigned short* WpTh = (unsigned short*)(base);             // bf16
  unsigned short* WpTl = (unsigned short*)(base + 2097152);
  unsigned short* Whh  = (unsigned short*)(base + 4194304);
  unsigned short* Whl  = (unsigned short*)(base + 6291456);
  unsigned short* Wch  = (unsigned short*)(base + 8388608);   // f16
  unsigned short* Wcl  = (unsigned short*)(base + 10485760);
  float*           bc  = (float*)(base + 12582912);
  float*          part = (float*)(base + 12582912 + 65536);

  prep_kernel<<<35072, 256, 0, stream>>>(x, W_proj, W_hid, b_proj, b_hid,
                                         Xh, WpTh, WpTl, Whh, Whl, bc);
  gemm_w<<<256, 256, 0, stream>>>(Whh, Whl, WpTh, WpTl, Pws);
  wsplit_kernel<<<1024, 256, 0, stream>>>(Pws, Wch, Wcl);
  gemm_main<<<512, 512, 0, stream>>>(Xh, Wch, Wcl, bc, Y2, M);
  lif_part_kernel<<<256, 256, 0, stream>>>(Y2, part);
  head_kernel<<<320, 64, 0, stream>>>(part, W_out, b_out, out);
}

// Round 8
// 341.741 us; speedup vs baseline: 1.1326x; 1.0479x over previous
//
#include <hip/hip_runtime.h>
#include <stdint.h>

// SNN pipeline, algebraically fused: y2 = x @ (Wh@Wp)^T + (Wh@bp + bh), then
// T-parallel LIF scan (shadowing warm-up), pool+head.
// r10: 256^2 8-wave 4-phase gemm_main (126-132us, conflicts 0, reproduced 4x;
//   r11/r12/r14 variants all regressed -- frozen). r15: unbundled r14 -> best
//   358us. Accounting model (fits r0..r15): total = gemm_main + kernel-sum +
//   ~128us launch-interval constant (~20us/dispatch).
// r16: (a) x->f16 pass merged INTO gemm_w launch (disjoint block ranges;
//   gemm_w = 256 blocks low-occupancy MFMA, x = 32768 HBM-bound blocks ->
//   complementary overlap). (b) wsplit+Pws eliminated: full-K 64x64-tile
//   gemm_w (256 blocks = full chip) writes f16 hi/lo directly. 6 -> 5
//   launches.

typedef short v8s __attribute__((ext_vector_type(8)));
typedef _Float16 v8h __attribute__((ext_vector_type(8)));
typedef float v4f __attribute__((ext_vector_type(4)));

#define GAS __attribute__((address_space(1)))
#define LAS __attribute__((address_space(3)))

__device__ __forceinline__ unsigned short f2bf(float f) {
  unsigned int u = __float_as_uint(f);
  u += 0x7fffu + ((u >> 16) & 1u);   // round-to-nearest-even
  return (unsigned short)(u >> 16);
}
__device__ __forceinline__ float bf2f(unsigned short h) {
  return __uint_as_float(((unsigned int)h) << 16);
}
__device__ __forceinline__ unsigned short f2h(float f) {       // f32->f16 RNE
  union { _Float16 h; unsigned short u; } c;
  c.h = (_Float16)f;
  return c.u;
}
__device__ __forceinline__ float h2f(unsigned short u) {
  union { unsigned short u; _Float16 h; } c;
  c.u = u;
  return (float)c.h;
}

__device__ __forceinline__ void gld_lds16(const void* g, void* l) {
  __builtin_amdgcn_global_load_lds((const GAS void*)g, (LAS void*)l, 16, 0, 0);
}

__device__ __forceinline__ void split4(const float4 x, ushort4* h, ushort4* l) {
  h->x = f2bf(x.x); l->x = f2bf(x.x - bf2f(h->x));
  h->y = f2bf(x.y); l->y = f2bf(x.y - bf2f(h->y));
  h->z = f2bf(x.z); l->z = f2bf(x.z - bf2f(h->z));
  h->w = f2bf(x.w); l->w = f2bf(x.w - bf2f(h->w));
}

// Weight preprocessing (weights only; x->f16 lives in gemm_wx):
//  [0, 1024):    transpose+split W_proj -> WpT bf16 hi/lo
//  [1024, 2048): split W_hid -> Wh bf16 hi/lo
//  [2048, 2304): bc[g] = Wh[g,:].b_proj + b_hid[g]  (4 waves/block)
__global__ void __launch_bounds__(256) prep_kernel(
    const float* __restrict__ W_proj, const float* __restrict__ W_hid,
    const float* __restrict__ b_proj, const float* __restrict__ b_hid,
    unsigned short* __restrict__ WpTh, unsigned short* __restrict__ WpTl,
    unsigned short* __restrict__ Whh, unsigned short* __restrict__ Whl,
    float* __restrict__ bc) {
  __shared__ float t[32][33];
  const int blk = blockIdx.x, tid = threadIdx.x;
  if (blk < 1024) {
    const int tx = tid & 31, ty = tid >> 5;  // 32x8
    const int bx = blk & 31, by = blk >> 5;
    const int xc = bx * 32 + tx;
    const int yb = by * 32;
#pragma unroll
    for (int j = 0; j < 4; ++j) t[ty + 8 * j][tx] = W_proj[(size_t)(yb + ty + 8 * j) * 1024 + xc];
    __syncthreads();
    const int xo = yb + tx;
#pragma unroll
    for (int j = 0; j < 4; ++j) {
      const float v = t[tx][ty + 8 * j];
      const unsigned short h = f2bf(v);
      const size_t o = (size_t)(bx * 32 + ty + 8 * j) * 1024 + xo;
      WpTh[o] = h;
      WpTl[o] = f2bf(v - bf2f(h));
    }
  } else if (blk < 2048) {
    const int i = (blk - 1024) * 256 + tid;  // 262144 float4 = 1M floats
    float4 v = ((const float4*)W_hid)[i];
    ushort4 h, l;
    split4(v, &h, &l);
    ((ushort4*)Whh)[i] = h;
    ((ushort4*)Whl)[i] = l;
  } else {
    const int g = (blk - 2048) * 4 + (tid >> 6);
    const int lane = tid & 63;
    const float* wr = W_hid + (size_t)g * 1024;
    float s = 0.f;
#pragma unroll
    for (int i = 0; i < 16; ++i) s += wr[lane + 64 * i] * b_proj[lane + 64 * i];
#pragma unroll
    for (int off = 32; off > 0; off >>= 1) s += __shfl_down(s, off);
    if (lane == 0) bc[g] = s + b_hid[g];
  }
}

// Fused: [0,256) = weight GEMM Wc = Wh @ WpT^T (full K, 64x64 tiles, bf16
// hi/lo 3-product, direct f16 hi/lo out); [256, 33024+256) = x -> f16 Xh.
// gemm blocks dispatch first (1/CU, MFMA-bound); x blocks backfill (HBM-
// bound) -> complementary overlap. XOR bank swizzle: read slot =
// quad^((r>>1)&3), staged via inverse-swizzled global source (identical
// formula pair to gemm_main, measured conflict-free there).
__global__ void __launch_bounds__(256, 2)
gemm_wx(const unsigned short* __restrict__ Ah, const unsigned short* __restrict__ Al,
        const unsigned short* __restrict__ Bh, const unsigned short* __restrict__ Bl,
        const float* __restrict__ x, unsigned short* __restrict__ Xh,
        unsigned short* __restrict__ outH, unsigned short* __restrict__ outL) {
  constexpr int K = 1024, N = 1024;
  __shared__ unsigned short lds[4][64 * 32];   // Ah|Al|Bh|Bl tiles, 16 KB

  const int blk = blockIdx.x, tid = threadIdx.x;

  if (blk >= 256) {   // ---- x -> f16 stream (8388608 float4) ----
    const int i = (blk - 256) * 256 + tid;
    float4 v = ((const float4*)x)[i];
    ushort4 h;
    h.x = f2h(v.x); h.y = f2h(v.y); h.z = f2h(v.z); h.w = f2h(v.w);
    ((ushort4*)Xh)[i] = h;
    return;
  }

  // ---- weight GEMM: 64x64 tile, 4 waves in 2x2, full K ----
  const int mt = blk & 15, nt = blk >> 4;
  const int m0 = mt * 64, n0 = nt * 64;

  const int lane = tid & 63, wave = tid >> 6;
  const int wm = (wave >> 1) * 32, wn = (wave & 1) * 32;
  const int quad = lane >> 4, r = lane & 15;
  const int cs = (quad ^ ((r >> 1) & 3)) * 8;          // swizzled read col
  const int srow = tid >> 2;                           // 0..63
  const int sslot = (tid & 3) ^ ((tid >> 3) & 3);      // inverse-swz source

  const unsigned short* gAh = Ah + (size_t)(m0 + srow) * K + sslot * 8;
  const unsigned short* gAl = Al + (size_t)(m0 + srow) * K + sslot * 8;
  const unsigned short* gBh = Bh + (size_t)(n0 + srow) * K + sslot * 8;
  const unsigned short* gBl = Bl + (size_t)(n0 + srow) * K + sslot * 8;

  v4f acc[2][2];
#pragma unroll
  for (int i = 0; i < 2; ++i)
#pragma unroll
    for (int j = 0; j < 2; ++j) acc[i][j] = v4f{0.f, 0.f, 0.f, 0.f};

  for (int kt = 0; kt < K; kt += 32) {
    gld_lds16(gAh + kt, &lds[0][tid * 8]);
    gld_lds16(gAl + kt, &lds[1][tid * 8]);
    gld_lds16(gBh + kt, &lds[2][tid * 8]);
    gld_lds16(gBl + kt, &lds[3][tid * 8]);
    __syncthreads();

    v8s ah[2], al[2], bh[2], bl[2];
#pragma unroll
    for (int i = 0; i < 2; ++i) {
      ah[i] = *(const v8s*)&lds[0][(wm + i * 16 + r) * 32 + cs];
      al[i] = *(const v8s*)&lds[1][(wm + i * 16 + r) * 32 + cs];
      bh[i] = *(const v8s*)&lds[2][(wn + i * 16 + r) * 32 + cs];
      bl[i] = *(const v8s*)&lds[3][(wn + i * 16 + r) * 32 + cs];
    }
#pragma unroll
    for (int i = 0; i < 2; ++i)
#pragma unroll
      for (int j = 0; j < 2; ++j) {
        acc[i][j] = __builtin_amdgcn_mfma_f32_16x16x32_bf16(ah[i], bh[j], acc[i][j], 0, 0, 0);
        acc[i][j] = __builtin_amdgcn_mfma_f32_16x16x32_bf16(ah[i], bl[j], acc[i][j], 0, 0, 0);
        acc[i][j] = __builtin_amdgcn_mfma_f32_16x16x32_bf16(al[i], bh[j], acc[i][j], 0, 0, 0);
      }
    __syncthreads();
  }

#pragma unroll
  for (int i = 0; i < 2; ++i)
#pragma unroll
    for (int j = 0; j < 2; ++j) {
      const int gn = n0 + wn + j * 16 + r;
#pragma unroll
      for (int q2 = 0; q2 < 4; ++q2) {
        const int gm = m0 + wm + i * 16 + quad * 4 + q2;
        const float y = acc[i][j][q2];
        const unsigned short h = f2h(y);
        const size_t o = (size_t)gm * N + gn;
        outH[o] = h;
        outL[o] = f2h(y - h2f(h));
      }
    }
}

// Main GEMM: Y2(f16) = Xf16 @ Wc^T + bc. 256x256 tile, 8 waves (2Mx4N) each
// owning 128x64. BK=32, both B planes per K-step -> 64 MFMA/wave/K-step split
// into 4 phases x 16 MFMA. Triple-buffered LDS (3 x 48KB). ds_reads issued
// ONE PHASE AHEAD of their MFMA use, with counted lgkmcnt(N). Counted
// vmcnt(4) at P1 confirms buffer nxt one phase before P2's cross-K-step
// prefetch reads it. Bank swizzle via pre-swizzled global source + swizzled
// ds_read addr (rule #21). [r10-exact: 126-132us / MfmaUtil 47 / conflicts 0,
// reproduced 4x; r11/r12/r14 variants all regressed -- do not modify.]
__global__ void __launch_bounds__(512, 2)
gemm_main(const unsigned short* __restrict__ Ah,
          const unsigned short* __restrict__ Bh, const unsigned short* __restrict__ Bl,
          const float* __restrict__ bias, unsigned short* __restrict__ outH, int M) {
  constexpr int K = 1024, N = 1024;
  __shared__ unsigned short lA[3][8192];   // 48 KB
  __shared__ unsigned short lB0[3][8192];  // 48 KB
  __shared__ unsigned short lB1[3][8192];  // 48 KB

  const int tid = threadIdx.x;
  const int band = (M >> 8) >> 3;            // 16 for M=32768
  const int c = blockIdx.x & 7, idx = blockIdx.x >> 3;   // 512 blocks, %8==0
  const int mt = c * band + (idx >> 2), nt = idx & 3;
  const int m0 = mt * 256, n0 = nt * 256;

  const int lane = tid & 63, wave = tid >> 6;
  const int wm = (wave >> 2) * 128, wn = (wave & 3) * 64;
  const int quad = lane >> 4, r = lane & 15;
  // swizzled read column (shorts): physical slot = quad ^ ((row>>1)&3)
  const int cs = (quad ^ ((r >> 1) & 3)) * 8;
  const int aoff = (wm + r) * 32 + cs;   // + i*512 per fragment
  const int boff = (wn + r) * 32 + cs;   // + j*512 per fragment

  // staging: thread t -> tile row t>>2, linear LDS slot t&3; global source
  // slot inverse-swizzled so the LDS image is the swizzled layout.
  const int srow = tid >> 2;                           // 0..127 (+128 call 1)
  const int sslot = (tid & 3) ^ ((tid >> 3) & 3);      // same for row+128

  const unsigned short* gA   = Ah + (size_t)(m0 + srow) * K + sslot * 8;
  const unsigned short* gB0p = Bh + (size_t)(n0 + srow) * K + sslot * 8;
  const unsigned short* gB1p = Bl + (size_t)(n0 + srow) * K + sslot * 8;

  v4f acc[8][4];
#pragma unroll
  for (int i = 0; i < 8; ++i)
#pragma unroll
    for (int j = 0; j < 4; ++j) acc[i][j] = v4f{0.f, 0.f, 0.f, 0.f};

  // buffer rotation pointers: cur / nxt / nx2 (staging target)
  unsigned short *Ac = lA[0],  *An = lA[1],  *A2 = lA[2];
  unsigned short *Bc = lB0[0], *Bn = lB0[1], *B2 = lB0[2];
  unsigned short *Cc = lB1[0], *Cn = lB1[1], *C2 = lB1[2];

  // prologue: stage K-step 0 -> buf0, K-step 1 -> buf1 (6 loads each)
  gld_lds16(gA,              &Ac[tid * 8]);
  gld_lds16(gA + 128 * K,    &Ac[4096 + tid * 8]);
  gld_lds16(gB0p,            &Bc[tid * 8]);
  gld_lds16(gB0p + 128 * K,  &Bc[4096 + tid * 8]);
  gld_lds16(gB1p,            &Cc[tid * 8]);
  gld_lds16(gB1p + 128 * K,  &Cc[4096 + tid * 8]);
  gld_lds16(gA + 32,             &An[tid * 8]);
  gld_lds16(gA + 32 + 128 * K,   &An[4096 + tid * 8]);
  gld_lds16(gB0p + 32,           &Bn[tid * 8]);
  gld_lds16(gB0p + 32 + 128 * K, &Bn[4096 + tid * 8]);
  gld_lds16(gB1p + 32,           &Cn[tid * 8]);
  gld_lds16(gB1p + 32 + 128 * K, &Cn[4096 + tid * 8]);
  asm volatile("s_waitcnt vmcnt(6)" ::: "memory");   // buf0 complete
  __builtin_amdgcn_s_barrier();
  __builtin_amdgcn_sched_barrier(0);

  // preload P0 operands of K-step 0 from buf0
  v8h ah[4], bh[4];
#pragma unroll
  for (int i = 0; i < 4; ++i) ah[i] = *(const v8h*)&Ac[aoff + i * 512];
#pragma unroll
  for (int j = 0; j < 4; ++j) bh[j] = *(const v8h*)&Bc[boff + j * 512];
  __builtin_amdgcn_sched_barrier(0);

#pragma unroll 1
  for (int t = 0; t < 32; ++t) {
    const int kp = (t + 2) * 32;
    const bool pf = (t < 30);
    v8h bl[4], ah2[4], anx[4], bnx[4];

    // ---- P0: read bl(cur); stage A -> nx2; MFMA ah x bh ----
#pragma unroll
    for (int j = 0; j < 4; ++j) bl[j] = *(const v8h*)&Cc[boff + j * 512];
    if (pf) {
      gld_lds16(gA + kp,           &A2[tid * 8]);
      gld_lds16(gA + kp + 128 * K, &A2[4096 + tid * 8]);
    }
    __builtin_amdgcn_sched_barrier(0);
    __builtin_amdgcn_s_barrier();
    asm volatile("s_waitcnt lgkmcnt(4)" ::: "memory");  // ah,bh ready; bl in flight
    __builtin_amdgcn_sched_barrier(0);
    __builtin_amdgcn_s_setprio(1);
#pragma unroll
    for (int i = 0; i < 4; ++i)
#pragma unroll
      for (int j = 0; j < 4; ++j)
        acc[i][j] = __builtin_amdgcn_mfma_f32_16x16x32_f16(ah[i], bh[j], acc[i][j], 0, 0, 0);
    __builtin_amdgcn_s_setprio(0);
    __builtin_amdgcn_sched_barrier(0);
    __builtin_amdgcn_s_barrier();

    // ---- P1: read ah2(cur); stage B0 -> nx2; MFMA ah x bl ----
#pragma unroll
    for (int i = 0; i < 4; ++i) ah2[i] = *(const v8h*)&Ac[aoff + (4 + i) * 512];
    if (pf) {
      gld_lds16(gB0p + kp,           &B2[tid * 8]);
      gld_lds16(gB0p + kp + 128 * K, &B2[4096 + tid * 8]);
    }
    __builtin_amdgcn_sched_barrier(0);
    __builtin_amdgcn_s_barrier();
    // vmcnt(4): the 4 newest are this iter's A+B0 stages; everything older
    // (buffer nxt's 6 loads) confirmed -> P2 may read buf nxt after barrier.
    asm volatile("s_waitcnt vmcnt(4) lgkmcnt(4)" ::: "memory");  // bl ready
    __builtin_amdgcn_sched_barrier(0);
    __builtin_amdgcn_s_setprio(1);
#pragma unroll
    for (int i = 0; i < 4; ++i)
#pragma unroll
      for (int j = 0; j < 4; ++j)
        acc[i][j] = __builtin_amdgcn_mfma_f32_16x16x32_f16(ah[i], bl[j], acc[i][j], 0, 0, 0);
    __builtin_amdgcn_s_setprio(0);
    __builtin_amdgcn_sched_barrier(0);
    __builtin_amdgcn_s_barrier();

    // ---- P2: read next K-step's ah,bh from buf nxt; stage B1 -> nx2;
    //          MFMA ah2 x bh ----
#pragma unroll
    for (int i = 0; i < 4; ++i) anx[i] = *(const v8h*)&An[aoff + i * 512];
#pragma unroll
    for (int j = 0; j < 4; ++j) bnx[j] = *(const v8h*)&Bn[boff + j * 512];
    if (pf) {
      gld_lds16(gB1p + kp,           &C2[tid * 8]);
      gld_lds16(gB1p + kp + 128 * K, &C2[4096 + tid * 8]);
    }
    __builtin_amdgcn_sched_barrier(0);
    __builtin_amdgcn_s_barrier();
    asm volatile("s_waitcnt lgkmcnt(8)" ::: "memory");  // ah2 ready; anx,bnx in flight
    __builtin_amdgcn_sched_barrier(0);
    __builtin_amdgcn_s_setprio(1);
#pragma unroll
    for (int i = 0; i < 4; ++i)
#pragma unroll
      for (int j = 0; j < 4; ++j)
        acc[4 + i][j] = __builtin_amdgcn_mfma_f32_16x16x32_f16(ah2[i], bh[j], acc[4 + i][j], 0, 0, 0);
    __builtin_amdgcn_s_setprio(0);
    __builtin_amdgcn_sched_barrier(0);
    __builtin_amdgcn_s_barrier();

    // ---- P3: MFMA ah2 x bl (all operands confirmed earlier) ----
    __builtin_amdgcn_s_setprio(1);
#pragma unroll
    for (int i = 0; i < 4; ++i)
#pragma unroll
      for (int j = 0; j < 4; ++j)
        acc[4 + i][j] = __builtin_amdgcn_mfma_f32_16x16x32_f16(ah2[i], bl[j], acc[4 + i][j], 0, 0, 0);
    __builtin_amdgcn_s_setprio(0);
    __builtin_amdgcn_sched_barrier(0);
    __builtin_amdgcn_s_barrier();

    // rotate buffers; promote prefetched operands
    unsigned short* tp;
    tp = Ac; Ac = An; An = A2; A2 = tp;
    tp = Bc; Bc = Bn; Bn = B2; B2 = tp;
    tp = Cc; Cc = Cn; Cn = C2; C2 = tp;
#pragma unroll
    for (int i = 0; i < 4; ++i) { ah[i] = anx[i]; bh[i] = bnx[i]; }
  }

  // epilogue: C[m = quad*4+q2][n = lane&15]; store f16 with bias
  float bv[4];
#pragma unroll
  for (int j = 0; j < 4; ++j) bv[j] = bias[n0 + wn + j * 16 + r];
#pragma unroll
  for (int i = 0; i < 8; ++i)
#pragma unroll
    for (int j = 0; j < 4; ++j) {
      const int gn = n0 + wn + j * 16 + r;
#pragma unroll
      for (int q2 = 0; q2 < 4; ++q2) {
        const int gm = m0 + wm + i * 16 + quad * 4 + q2;
        outH[(size_t)gm * N + gn] = f2h(acc[i][j][q2] + bv[j]);
      }
    }
}

// T-parallel LIF over f16 y2: 8 chunks of 128 steps, 32-step shadowing
// warm-up. 4 channels/thread, ushort4 loads.
__global__ void __launch_bounds__(256) lif_part_kernel(const unsigned short* __restrict__ y2,
                                                       float* __restrict__ part) {
  const int gid = blockIdx.x * 256 + threadIdx.x;   // 65536 threads
  const int chunk = gid >> 13;                      // 8192 threads/chunk
  const int c4 = (gid & 8191) << 2;                 // base channel, %4==0
  const unsigned short* p = y2 + ((size_t)(c4 >> 10) << 20) + (c4 & 1023);
  const int t0 = chunk << 7;
  float v0 = 0.f, v1 = 0.f, v2 = 0.f, v3 = 0.f;
  if (chunk) {  // uniform per wave (8192 % 64 == 0)
    const unsigned short* pw = p + (size_t)(t0 - 32) * 1024;
    for (int b = 0; b < 32; b += 16) {
      ushort4 x[16];
#pragma unroll
      for (int i = 0; i < 16; ++i) x[i] = *(const ushort4*)&pw[(size_t)(b + i) * 1024];
#pragma unroll
      for (int i = 0; i < 16; ++i) {
        v0 += (h2f(x[i].x) - v0) * 0.5f; if (v0 >= 1.0f) v0 -= 1.0f;
        v1 += (h2f(x[i].y) - v1) * 0.5f; if (v1 >= 1.0f) v1 -= 1.0f;
        v2 += (h2f(x[i].z) - v2) * 0.5f; if (v2 >= 1.0f) v2 -= 1.0f;
        v3 += (h2f(x[i].w) - v3) * 0.5f; if (v3 >= 1.0f) v3 -= 1.0f;
      }
    }
  }
  float c0 = 0.f, c1 = 0.f, c2 = 0.f, c3 = 0.f;
  const unsigned short* pm = p + (size_t)t0 * 1024;
  for (int b = 0; b < 128; b += 16) {
    ushort4 x[16];
#pragma unroll
    for (int i = 0; i < 16; ++i) x[i] = *(const ushort4*)&pm[(size_t)(b + i) * 1024];
#pragma unroll
    for (int i = 0; i < 16; ++i) {
      float s;
      v0 += (h2f(x[i].x) - v0) * 0.5f; s = (v0 >= 1.0f) ? 1.0f : 0.0f; c0 += s; v0 -= s;
      v1 += (h2f(x[i].y) - v1) * 0.5f; s = (v1 >= 1.0f) ? 1.0f : 0.0f; c1 += s; v1 -= s;
      v2 += (h2f(x[i].z) - v2) * 0.5f; s = (v2 >= 1.0f) ? 1.0f : 0.0f; c2 += s; v2 -= s;
      v3 += (h2f(x[i].w) - v3) * 0.5f; s = (v3 >= 1.0f) ? 1.0f : 0.0f; c3 += s; v3 -= s;
    }
  }
  float4 o; o.x = c0; o.y = c1; o.z = c2; o.w = c3;
  *(float4*)&part[(size_t)chunk * 32768 + c4] = o;
}

// out[b,o] = (sum_c part[c][b,:]).W_out[o,:]/1024 + b_out[o]; one wave each.
__global__ void __launch_bounds__(64) head_kernel(const float* __restrict__ part,
                                                  const float* __restrict__ W_out,
                                                  const float* __restrict__ b_out,
                                                  float* __restrict__ out) {
  int blk = blockIdx.x;          // 0..319
  int b = blk / 10, o = blk % 10;
  int lane = threadIdx.x;
  const float* wr = W_out + o * 1024;
  float s = 0.f;
#pragma unroll
  for (int i = 0; i < 16; ++i) {
    const int ch = b * 1024 + lane + 64 * i;
    float p = 0.f;
#pragma unroll
    for (int c = 0; c < 8; ++c) p += part[c * 32768 + ch];
    s += p * wr[lane + 64 * i];
  }
#pragma unroll
  for (int off = 32; off > 0; off >>= 1) s += __shfl_down(s, off);
  if (lane == 0) out[b * 10 + o] = s * (1.0f / 1024.0f) + b_out[o];
}

extern "C" void kernel_launch(void* const* d_in, const int* in_sizes, int n_in,
                              void* d_out, int out_size, void* d_ws, size_t ws_size,
                              hipStream_t stream) {
  const float* x      = (const float*)d_in[0];
  const float* W_proj = (const float*)d_in[1];
  const float* b_proj = (const float*)d_in[2];
  const float* W_hid  = (const float*)d_in[3];
  const float* b_hid  = (const float*)d_in[4];
  const float* W_out  = (const float*)d_in[5];
  const float* b_out  = (const float*)d_in[6];
  float* out = (float*)d_out;

  const int M = 32768;  // B*T

  // Workspace (~143 MB): Xh f16 [64M] | Y2 f16 [64M] | weights | bc | part
  char* ws = (char*)d_ws;
  unsigned short* Xh   = (unsigned short*)(ws);
  unsigned short* Y2   = (unsigned short*)(ws + 67108864);
  char* base = ws + 134217728;
  unsigned short* WpTh = (unsigned short*)(base);             // bf16
  unsigned short* WpTl = (unsigned short*)(base + 2097152);
  unsigned short* Whh  = (unsigned short*)(base + 4194304);
  unsigned short* Whl  = (unsigned short*)(base + 6291456);
  unsigned short* Wch  = (unsigned short*)(base + 8388608);   // f16
  unsigned short* Wcl  = (unsigned short*)(base + 10485760);
  float*           bc  = (float*)(base + 12582912);
  float*          part = (float*)(base + 12582912 + 65536);

  prep_kernel<<<2304, 256, 0, stream>>>(W_proj, W_hid, b_proj, b_hid,
                                        WpTh, WpTl, Whh, Whl, bc);
  // Wc[g,d] = sum_h Wh[g,h] * WpT[d,h] (blocks 0..255) || x->Xh (rest)
  gemm_wx<<<33024, 256, 0, stream>>>(Whh, Whl, WpTh, WpTl, x, Xh, Wch, Wcl);
  gemm_main<<<512, 512, 0, stream>>>(Xh, Wch, Wcl, bc, Y2, M);
  lif_part_kernel<<<256, 256, 0, stream>>>(Y2, part);
  head_kernel<<<320, 64, 0, stream>>>(part, W_out, b_out, out);
}

// Round 9
// 315.520 us; speedup vs baseline: 1.2267x; 1.0831x over previous
//
#include <hip/hip_runtime.h>
#include <stdint.h>

// SNN pipeline, algebraically fused: y2 = x @ (Wh@Wp)^T + (Wh@bp + bh), then
// T-parallel LIF scan, pool+head.
// r10: 256^2 8-wave 4-phase gemm_main schedule (frozen; 4 rebuild attempts
//   regressed). r16: gemm_w+x-pass merged, wsplit gone -> 341.7us. Refit:
//   ~130us of total is harness-side (graph replay/reset), not launch gaps.
// r17: (a) B single f16 plane in gemm_main (was hi/lo 2-product): halves
//   MFMA work -> 2 phases, 4 barriers/K-step, LDS 96KB. Error budget: B-f16
//   adds ~2-5e-4 in quadrature to existing ~5e-4 A-f16 + Y2-f16 error ->
//   absmax predicted ~5-9e-4 (was 4.88e-4). (b) lif+head merged, warm-up
//   approximation removed (exact per-channel scan, 1 thread/channel),
//   atomicAdd f32 combine, out zero-init in prep. 4 launches.

typedef short v8s __attribute__((ext_vector_type(8)));
typedef _Float16 v8h __attribute__((ext_vector_type(8)));
typedef float v4f __attribute__((ext_vector_type(4)));

#define GAS __attribute__((address_space(1)))
#define LAS __attribute__((address_space(3)))
#define SB __builtin_amdgcn_sched_barrier(0)

__device__ __forceinline__ unsigned short f2bf(float f) {
  unsigned int u = __float_as_uint(f);
  u += 0x7fffu + ((u >> 16) & 1u);   // round-to-nearest-even
  return (unsigned short)(u >> 16);
}
__device__ __forceinline__ float bf2f(unsigned short h) {
  return __uint_as_float(((unsigned int)h) << 16);
}
__device__ __forceinline__ unsigned short f2h(float f) {       // f32->f16 RNE
  union { _Float16 h; unsigned short u; } c;
  c.h = (_Float16)f;
  return c.u;
}
__device__ __forceinline__ float h2f(unsigned short u) {
  union { unsigned short u; _Float16 h; } c;
  c.u = u;
  return (float)c.h;
}

__device__ __forceinline__ void gld_lds16(const void* g, void* l) {
  __builtin_amdgcn_global_load_lds((const GAS void*)g, (LAS void*)l, 16, 0, 0);
}

__device__ __forceinline__ void split4(const float4 x, ushort4* h, ushort4* l) {
  h->x = f2bf(x.x); l->x = f2bf(x.x - bf2f(h->x));
  h->y = f2bf(x.y); l->y = f2bf(x.y - bf2f(h->y));
  h->z = f2bf(x.z); l->z = f2bf(x.z - bf2f(h->z));
  h->w = f2bf(x.w); l->w = f2bf(x.w - bf2f(h->w));
}

// Weight preprocessing (weights only):
//  [0, 1024):    transpose+split W_proj -> WpT bf16 hi/lo
//  [1024, 2048): split W_hid -> Wh bf16 hi/lo
//  [2048, 2304): bc[g] = Wh[g,:].b_proj + b_hid[g]  (4 waves/block)
//  [2304]:       zero-init out (for lif_head atomicAdd)
__global__ void __launch_bounds__(256) prep_kernel(
    const float* __restrict__ W_proj, const float* __restrict__ W_hid,
    const float* __restrict__ b_proj, const float* __restrict__ b_hid,
    unsigned short* __restrict__ WpTh, unsigned short* __restrict__ WpTl,
    unsigned short* __restrict__ Whh, unsigned short* __restrict__ Whl,
    float* __restrict__ bc, float* __restrict__ out) {
  __shared__ float t[32][33];
  const int blk = blockIdx.x, tid = threadIdx.x;
  if (blk < 1024) {
    const int tx = tid & 31, ty = tid >> 5;  // 32x8
    const int bx = blk & 31, by = blk >> 5;
    const int xc = bx * 32 + tx;
    const int yb = by * 32;
#pragma unroll
    for (int j = 0; j < 4; ++j) t[ty + 8 * j][tx] = W_proj[(size_t)(yb + ty + 8 * j) * 1024 + xc];
    __syncthreads();
    const int xo = yb + tx;
#pragma unroll
    for (int j = 0; j < 4; ++j) {
      const float v = t[tx][ty + 8 * j];
      const unsigned short h = f2bf(v);
      const size_t o = (size_t)(bx * 32 + ty + 8 * j) * 1024 + xo;
      WpTh[o] = h;
      WpTl[o] = f2bf(v - bf2f(h));
    }
  } else if (blk < 2048) {
    const int i = (blk - 1024) * 256 + tid;  // 262144 float4 = 1M floats
    float4 v = ((const float4*)W_hid)[i];
    ushort4 h, l;
    split4(v, &h, &l);
    ((ushort4*)Whh)[i] = h;
    ((ushort4*)Whl)[i] = l;
  } else if (blk < 2304) {
    const int g = (blk - 2048) * 4 + (tid >> 6);
    const int lane = tid & 63;
    const float* wr = W_hid + (size_t)g * 1024;
    float s = 0.f;
#pragma unroll
    for (int i = 0; i < 16; ++i) s += wr[lane + 64 * i] * b_proj[lane + 64 * i];
#pragma unroll
    for (int off = 32; off > 0; off >>= 1) s += __shfl_down(s, off);
    if (lane == 0) bc[g] = s + b_hid[g];
  } else {
    if (tid < 320) out[tid] = 0.f;
  }
}

// Fused: [0,256) = weight GEMM Wc = Wh @ WpT^T (full K, 64x64 tiles, bf16
// hi/lo 3-product -> near-fp32, rounded ONCE to f16 out); [256,33280) =
// x -> f16 Xh stream. Complementary overlap (MFMA-bound || HBM-bound).
__global__ void __launch_bounds__(256, 2)
gemm_wx(const unsigned short* __restrict__ Ah, const unsigned short* __restrict__ Al,
        const unsigned short* __restrict__ Bh, const unsigned short* __restrict__ Bl,
        const float* __restrict__ x, unsigned short* __restrict__ Xh,
        unsigned short* __restrict__ outH) {
  constexpr int K = 1024, N = 1024;
  __shared__ unsigned short lds[4][64 * 32];   // Ah|Al|Bh|Bl tiles, 16 KB

  const int blk = blockIdx.x, tid = threadIdx.x;

  if (blk >= 256) {   // ---- x -> f16 stream (8388608 float4) ----
    const int i = (blk - 256) * 256 + tid;
    float4 v = ((const float4*)x)[i];
    ushort4 h;
    h.x = f2h(v.x); h.y = f2h(v.y); h.z = f2h(v.z); h.w = f2h(v.w);
    ((ushort4*)Xh)[i] = h;
    return;
  }

  // ---- weight GEMM: 64x64 tile, 4 waves in 2x2, full K ----
  const int mt = blk & 15, nt = blk >> 4;
  const int m0 = mt * 64, n0 = nt * 64;

  const int lane = tid & 63, wave = tid >> 6;
  const int wm = (wave >> 1) * 32, wn = (wave & 1) * 32;
  const int quad = lane >> 4, r = lane & 15;
  const int cs = (quad ^ ((r >> 1) & 3)) * 8;          // swizzled read col
  const int srow = tid >> 2;                           // 0..63
  const int sslot = (tid & 3) ^ ((tid >> 3) & 3);      // inverse-swz source

  const unsigned short* gAh = Ah + (size_t)(m0 + srow) * K + sslot * 8;
  const unsigned short* gAl = Al + (size_t)(m0 + srow) * K + sslot * 8;
  const unsigned short* gBh = Bh + (size_t)(n0 + srow) * K + sslot * 8;
  const unsigned short* gBl = Bl + (size_t)(n0 + srow) * K + sslot * 8;

  v4f acc[2][2];
#pragma unroll
  for (int i = 0; i < 2; ++i)
#pragma unroll
    for (int j = 0; j < 2; ++j) acc[i][j] = v4f{0.f, 0.f, 0.f, 0.f};

  for (int kt = 0; kt < K; kt += 32) {
    gld_lds16(gAh + kt, &lds[0][tid * 8]);
    gld_lds16(gAl + kt, &lds[1][tid * 8]);
    gld_lds16(gBh + kt, &lds[2][tid * 8]);
    gld_lds16(gBl + kt, &lds[3][tid * 8]);
    __syncthreads();

    v8s ah[2], al[2], bh[2], bl[2];
#pragma unroll
    for (int i = 0; i < 2; ++i) {
      ah[i] = *(const v8s*)&lds[0][(wm + i * 16 + r) * 32 + cs];
      al[i] = *(const v8s*)&lds[1][(wm + i * 16 + r) * 32 + cs];
      bh[i] = *(const v8s*)&lds[2][(wn + i * 16 + r) * 32 + cs];
      bl[i] = *(const v8s*)&lds[3][(wn + i * 16 + r) * 32 + cs];
    }
#pragma unroll
    for (int i = 0; i < 2; ++i)
#pragma unroll
      for (int j = 0; j < 2; ++j) {
        acc[i][j] = __builtin_amdgcn_mfma_f32_16x16x32_bf16(ah[i], bh[j], acc[i][j], 0, 0, 0);
        acc[i][j] = __builtin_amdgcn_mfma_f32_16x16x32_bf16(ah[i], bl[j], acc[i][j], 0, 0, 0);
        acc[i][j] = __builtin_amdgcn_mfma_f32_16x16x32_bf16(al[i], bh[j], acc[i][j], 0, 0, 0);
      }
    __syncthreads();
  }

#pragma unroll
  for (int i = 0; i < 2; ++i)
#pragma unroll
    for (int j = 0; j < 2; ++j) {
      const int gn = n0 + wn + j * 16 + r;
#pragma unroll
      for (int q2 = 0; q2 < 4; ++q2) {
        const int gm = m0 + wm + i * 16 + quad * 4 + q2;
        outH[(size_t)gm * N + gn] = f2h(acc[i][j][q2]);
      }
    }
}

// Main GEMM: Y2(f16) = Xf16 @ Wc(f16)^T + bc. 256x256 tile, 8 waves (2Mx4N)
// each owning 128x64. BK=32, SINGLE B plane -> 32 MFMA/wave/K-step in 2
// phases x 16. Triple-buffered LDS (2 arrays x 24KB x ... = 96 KB total).
// r10 discipline kept: one-phase-ahead ds_reads w/ counted lgkmcnt(4);
// counted vmcnt(4) at P1 (pf-conditional: vmcnt(0) in tail) confirms buffer
// nxt before its reads; XOR swizzle both-sides (rule #21); setprio on MFMA.
__global__ void __launch_bounds__(512, 2)
gemm_main(const unsigned short* __restrict__ Ah,
          const unsigned short* __restrict__ Bh,
          const float* __restrict__ bias, unsigned short* __restrict__ outH, int M) {
  constexpr int K = 1024, N = 1024;
  __shared__ unsigned short lA[3][8192];   // 48 KB
  __shared__ unsigned short lB[3][8192];   // 48 KB

  const int tid = threadIdx.x;
  const int band = (M >> 8) >> 3;            // 16 for M=32768
  const int c = blockIdx.x & 7, idx = blockIdx.x >> 3;   // 512 blocks, %8==0
  const int mt = c * band + (idx >> 2), nt = idx & 3;
  const int m0 = mt * 256, n0 = nt * 256;

  const int lane = tid & 63, wave = tid >> 6;
  const int wm = (wave >> 2) * 128, wn = (wave & 3) * 64;
  const int quad = lane >> 4, r = lane & 15;
  // swizzled read column (shorts): physical slot = quad ^ ((row>>1)&3)
  const int cs = (quad ^ ((r >> 1) & 3)) * 8;
  const int aoff = (wm + r) * 32 + cs;   // + i*512 per fragment
  const int boff = (wn + r) * 32 + cs;   // + j*512 per fragment

  // staging: thread t -> tile row t>>2, linear LDS slot t&3; global source
  // slot inverse-swizzled so the LDS image is the swizzled layout.
  const int srow = tid >> 2;                           // 0..127 (+128 call 1)
  const int sslot = (tid & 3) ^ ((tid >> 3) & 3);      // same for row+128

  const unsigned short* gA = Ah + (size_t)(m0 + srow) * K + sslot * 8;
  const unsigned short* gB = Bh + (size_t)(n0 + srow) * K + sslot * 8;

  v4f acc[8][4];
#pragma unroll
  for (int i = 0; i < 8; ++i)
#pragma unroll
    for (int j = 0; j < 4; ++j) acc[i][j] = v4f{0.f, 0.f, 0.f, 0.f};

  // buffer rotation pointers: cur / nxt / nx2 (staging target)
  unsigned short *Ac = lA[0], *An = lA[1], *A2 = lA[2];
  unsigned short *Bc = lB[0], *Bn = lB[1], *B2 = lB[2];

  // prologue: stage K-step 0 -> buf0, K-step 1 -> buf1 (4 loads each)
  gld_lds16(gA,             &Ac[tid * 8]);
  gld_lds16(gA + 128 * K,   &Ac[4096 + tid * 8]);
  gld_lds16(gB,             &Bc[tid * 8]);
  gld_lds16(gB + 128 * K,   &Bc[4096 + tid * 8]);
  gld_lds16(gA + 32,            &An[tid * 8]);
  gld_lds16(gA + 32 + 128 * K,  &An[4096 + tid * 8]);
  gld_lds16(gB + 32,            &Bn[tid * 8]);
  gld_lds16(gB + 32 + 128 * K,  &Bn[4096 + tid * 8]);
  asm volatile("s_waitcnt vmcnt(4)" ::: "memory");   // buf0 complete
  __builtin_amdgcn_s_barrier();
  SB;

  // preload K-step 0 operands (8 reads; confirmed by first P0's lgkm(4))
  v8h ah[4], bh[4];
#pragma unroll
  for (int i = 0; i < 4; ++i) ah[i] = *(const v8h*)&Ac[aoff + i * 512];
#pragma unroll
  for (int j = 0; j < 4; ++j) bh[j] = *(const v8h*)&Bc[boff + j * 512];
  SB;

#pragma unroll 1
  for (int t = 0; t < 32; ++t) {
    const int kp = (t + 2) * 32;
    const bool pf = (t < 30);
    v8h ah2[4], anx[4], bnx[4];

    // ---- P0: read ah2(cur); stage A -> nx2; MFMA ah x bh ----
#pragma unroll
    for (int i = 0; i < 4; ++i) ah2[i] = *(const v8h*)&Ac[aoff + (4 + i) * 512];
    if (pf) {
      gld_lds16(gA + kp,           &A2[tid * 8]);
      gld_lds16(gA + kp + 128 * K, &A2[4096 + tid * 8]);
    }
    SB;
    __builtin_amdgcn_s_barrier();
    asm volatile("s_waitcnt lgkmcnt(4)" ::: "memory");  // ah,bh ready; ah2 in flight
    SB;
    __builtin_amdgcn_s_setprio(1);
#pragma unroll
    for (int i = 0; i < 4; ++i)
#pragma unroll
      for (int j = 0; j < 4; ++j)
        acc[i][j] = __builtin_amdgcn_mfma_f32_16x16x32_f16(ah[i], bh[j], acc[i][j], 0, 0, 0);
    __builtin_amdgcn_s_setprio(0);
    SB;
    __builtin_amdgcn_s_barrier();

    // ---- P1: stage B -> nx2; confirm buf nxt; read next K-step operands;
    //          MFMA ah2 x bh ----
    if (pf) {
      gld_lds16(gB + kp,           &B2[tid * 8]);
      gld_lds16(gB + kp + 128 * K, &B2[4096 + tid * 8]);
    }
    SB;
    __builtin_amdgcn_s_barrier();
    // vmcnt(4): 4 newest = this iter's A+B stages; older (buf nxt's 4)
    // confirmed -> An/Bn readable. lgkmcnt(0): ah2 confirmed (cheap).
    if (pf) asm volatile("s_waitcnt vmcnt(4) lgkmcnt(0)" ::: "memory");
    else    asm volatile("s_waitcnt vmcnt(0) lgkmcnt(0)" ::: "memory");
    SB;
#pragma unroll
    for (int i = 0; i < 4; ++i) anx[i] = *(const v8h*)&An[aoff + i * 512];
#pragma unroll
    for (int j = 0; j < 4; ++j) bnx[j] = *(const v8h*)&Bn[boff + j * 512];
    __builtin_amdgcn_s_setprio(1);
#pragma unroll
    for (int i = 0; i < 4; ++i)
#pragma unroll
      for (int j = 0; j < 4; ++j)
        acc[4 + i][j] = __builtin_amdgcn_mfma_f32_16x16x32_f16(ah2[i], bh[j], acc[4 + i][j], 0, 0, 0);
    __builtin_amdgcn_s_setprio(0);
    SB;
    __builtin_amdgcn_s_barrier();

    // rotate buffers; promote prefetched operands
    unsigned short* tp;
    tp = Ac; Ac = An; An = A2; A2 = tp;
    tp = Bc; Bc = Bn; Bn = B2; B2 = tp;
#pragma unroll
    for (int i = 0; i < 4; ++i) { ah[i] = anx[i]; bh[i] = bnx[i]; }
  }

  // epilogue: C[m = quad*4+q2][n = lane&15]; store f16 with bias
  float bv[4];
#pragma unroll
  for (int j = 0; j < 4; ++j) bv[j] = bias[n0 + wn + j * 16 + r];
#pragma unroll
  for (int i = 0; i < 8; ++i)
#pragma unroll
    for (int j = 0; j < 4; ++j) {
      const int gn = n0 + wn + j * 16 + r;
#pragma unroll
      for (int q2 = 0; q2 < 4; ++q2) {
        const int gm = m0 + wm + i * 16 + quad * 4 + q2;
        outH[(size_t)gm * N + gn] = f2h(acc[i][j][q2] + bv[j]);
      }
    }
}

// Fused LIF + head: one thread per (batch, channel), EXACT scan t=0..1023
// (no warm-up approximation -- identical op order to reference per channel).
// 256 blocks = 32 b x 8 quarters x 128 channels. Head: per-thread 10
// partials -> wave shfl reduce -> LDS across 2 waves -> atomicAdd (f32,
// device-scope) into out (zero-init'd in prep; q==0 adds b_out).
__global__ void __launch_bounds__(128) lif_head_kernel(
    const unsigned short* __restrict__ y2, const float* __restrict__ W_out,
    const float* __restrict__ b_out, float* __restrict__ out) {
  const int blk = blockIdx.x;
  const int b = blk >> 3, q = blk & 7;
  const int ch = q * 128 + threadIdx.x;
  const unsigned short* p = y2 + ((size_t)b << 20) + ch;   // row b*1024, t=0

  float v = 0.f, cnt = 0.f;
  for (int tb = 0; tb < 32; ++tb) {
    unsigned short xr[32];
#pragma unroll
    for (int i = 0; i < 32; ++i) xr[i] = p[(size_t)(tb * 32 + i) * 1024];
#pragma unroll
    for (int i = 0; i < 32; ++i) {
      v += (h2f(xr[i]) - v) * 0.5f;          // exact reference op order
      float s = (v >= 1.0f) ? 1.0f : 0.0f;
      cnt += s;
      v -= s;
    }
  }

  const float pooled = cnt * (1.0f / 1024.0f);
  float pp[10];
#pragma unroll
  for (int o = 0; o < 10; ++o) pp[o] = pooled * W_out[o * 1024 + ch];
#pragma unroll
  for (int o = 0; o < 10; ++o)
#pragma unroll
    for (int off = 32; off > 0; off >>= 1) pp[o] += __shfl_down(pp[o], off);

  __shared__ float ls[2][10];
  const int lane = threadIdx.x & 63, wv = threadIdx.x >> 6;
  if (lane == 0)
#pragma unroll
    for (int o = 0; o < 10; ++o) ls[wv][o] = pp[o];
  __syncthreads();
  if (threadIdx.x < 10) {
    float s = ls[0][threadIdx.x] + ls[1][threadIdx.x];
    if (q == 0) s += b_out[threadIdx.x];
    atomicAdd(&out[b * 10 + threadIdx.x], s);
  }
}

extern "C" void kernel_launch(void* const* d_in, const int* in_sizes, int n_in,
                              void* d_out, int out_size, void* d_ws, size_t ws_size,
                              hipStream_t stream) {
  const float* x      = (const float*)d_in[0];
  const float* W_proj = (const float*)d_in[1];
  const float* b_proj = (const float*)d_in[2];
  const float* W_hid  = (const float*)d_in[3];
  const float* b_hid  = (const float*)d_in[4];
  const float* W_out  = (const float*)d_in[5];
  const float* b_out  = (const float*)d_in[6];
  float* out = (float*)d_out;

  const int M = 32768;  // B*T

  // Workspace (~141 MB): Xh f16 [64M] | Y2 f16 [64M] | weights | bc
  char* ws = (char*)d_ws;
  unsigned short* Xh   = (unsigned short*)(ws);
  unsigned short* Y2   = (unsigned short*)(ws + 67108864);
  char* base = ws + 134217728;
  unsigned short* WpTh = (unsigned short*)(base);             // bf16
  unsigned short* WpTl = (unsigned short*)(base + 2097152);
  unsigned short* Whh  = (unsigned short*)(base + 4194304);
  unsigned short* Whl  = (unsigned short*)(base + 6291456);
  unsigned short* Wch  = (unsigned short*)(base + 8388608);   // f16 (single)
  float*           bc  = (float*)(base + 10485760);

  prep_kernel<<<2305, 256, 0, stream>>>(W_proj, W_hid, b_proj, b_hid,
                                        WpTh, WpTl, Whh, Whl, bc, out);
  // Wc[g,d] = sum_h Wh[g,h] * WpT[d,h] (blocks 0..255) || x->Xh (rest)
  gemm_wx<<<33024, 256, 0, stream>>>(Whh, Whl, WpTh, WpTl, x, Xh, Wch);
  gemm_main<<<512, 512, 0, stream>>>(Xh, Wch, bc, Y2, M);
  lif_head_kernel<<<256, 128, 0, stream>>>(Y2, W_out, b_out, out);
}

// Round 10
// 299.128 us; speedup vs baseline: 1.2939x; 1.0548x over previous
//
#include <hip/hip_runtime.h>
#include <stdint.h>

// SNN pipeline, algebraically fused: y2 = x @ (Wh@Wp)^T + (Wh@bp + bh), then
// T-parallel LIF scan, pool+head.
// r10 schedule discipline (frozen). r16: gemm_w+x merged -> 341.7us.
// r17: B single f16 plane (gemm_main 132->85.7us, absmax 4.88e-4->5.19e-4
//   exactly per quadrature model); lif+head fused BUT exact-scan variant was
//   latency-bound (2 waves/CU, ~40us vs 19us for the old chunked pair).
// r18: chunk-parallel fused lif_head restored: 1024 blocks (32b x 8chunk x
//   4quarter) x 256thr = 16 waves/CU; 32-step shadow warm-up (residual
//   0.5^32 ~ 2e-10, validated r0-r16); spike counts additive across chunks
//   -> per-block partial pooled.W atomicAdd'd into out. 4 launches.

typedef short v8s __attribute__((ext_vector_type(8)));
typedef _Float16 v8h __attribute__((ext_vector_type(8)));
typedef float v4f __attribute__((ext_vector_type(4)));

#define GAS __attribute__((address_space(1)))
#define LAS __attribute__((address_space(3)))
#define SB __builtin_amdgcn_sched_barrier(0)

__device__ __forceinline__ unsigned short f2bf(float f) {
  unsigned int u = __float_as_uint(f);
  u += 0x7fffu + ((u >> 16) & 1u);   // round-to-nearest-even
  return (unsigned short)(u >> 16);
}
__device__ __forceinline__ float bf2f(unsigned short h) {
  return __uint_as_float(((unsigned int)h) << 16);
}
__device__ __forceinline__ unsigned short f2h(float f) {       // f32->f16 RNE
  union { _Float16 h; unsigned short u; } c;
  c.h = (_Float16)f;
  return c.u;
}
__device__ __forceinline__ float h2f(unsigned short u) {
  union { unsigned short u; _Float16 h; } c;
  c.u = u;
  return (float)c.h;
}

__device__ __forceinline__ void gld_lds16(const void* g, void* l) {
  __builtin_amdgcn_global_load_lds((const GAS void*)g, (LAS void*)l, 16, 0, 0);
}

__device__ __forceinline__ void split4(const float4 x, ushort4* h, ushort4* l) {
  h->x = f2bf(x.x); l->x = f2bf(x.x - bf2f(h->x));
  h->y = f2bf(x.y); l->y = f2bf(x.y - bf2f(h->y));
  h->z = f2bf(x.z); l->z = f2bf(x.z - bf2f(h->z));
  h->w = f2bf(x.w); l->w = f2bf(x.w - bf2f(h->w));
}

// Weight preprocessing (weights only):
//  [0, 1024):    transpose+split W_proj -> WpT bf16 hi/lo
//  [1024, 2048): split W_hid -> Wh bf16 hi/lo
//  [2048, 2304): bc[g] = Wh[g,:].b_proj + b_hid[g]  (4 waves/block)
//  [2304]:       zero-init out (for lif_head atomicAdd)
__global__ void __launch_bounds__(256) prep_kernel(
    const float* __restrict__ W_proj, const float* __restrict__ W_hid,
    const float* __restrict__ b_proj, const float* __restrict__ b_hid,
    unsigned short* __restrict__ WpTh, unsigned short* __restrict__ WpTl,
    unsigned short* __restrict__ Whh, unsigned short* __restrict__ Whl,
    float* __restrict__ bc, float* __restrict__ out) {
  __shared__ float t[32][33];
  const int blk = blockIdx.x, tid = threadIdx.x;
  if (blk < 1024) {
    const int tx = tid & 31, ty = tid >> 5;  // 32x8
    const int bx = blk & 31, by = blk >> 5;
    const int xc = bx * 32 + tx;
    const int yb = by * 32;
#pragma unroll
    for (int j = 0; j < 4; ++j) t[ty + 8 * j][tx] = W_proj[(size_t)(yb + ty + 8 * j) * 1024 + xc];
    __syncthreads();
    const int xo = yb + tx;
#pragma unroll
    for (int j = 0; j < 4; ++j) {
      const float v = t[tx][ty + 8 * j];
      const unsigned short h = f2bf(v);
      const size_t o = (size_t)(bx * 32 + ty + 8 * j) * 1024 + xo;
      WpTh[o] = h;
      WpTl[o] = f2bf(v - bf2f(h));
    }
  } else if (blk < 2048) {
    const int i = (blk - 1024) * 256 + tid;  // 262144 float4 = 1M floats
    float4 v = ((const float4*)W_hid)[i];
    ushort4 h, l;
    split4(v, &h, &l);
    ((ushort4*)Whh)[i] = h;
    ((ushort4*)Whl)[i] = l;
  } else if (blk < 2304) {
    const int g = (blk - 2048) * 4 + (tid >> 6);
    const int lane = tid & 63;
    const float* wr = W_hid + (size_t)g * 1024;
    float s = 0.f;
#pragma unroll
    for (int i = 0; i < 16; ++i) s += wr[lane + 64 * i] * b_proj[lane + 64 * i];
#pragma unroll
    for (int off = 32; off > 0; off >>= 1) s += __shfl_down(s, off);
    if (lane == 0) bc[g] = s + b_hid[g];
  } else {
    if (tid < 320) out[tid] = 0.f;
  }
}

// Fused: [0,256) = weight GEMM Wc = Wh @ WpT^T (full K, 64x64 tiles, bf16
// hi/lo 3-product -> near-fp32, rounded ONCE to f16 out); [256,33280) =
// x -> f16 Xh stream. Complementary overlap (MFMA-bound || HBM-bound).
__global__ void __launch_bounds__(256, 2)
gemm_wx(const unsigned short* __restrict__ Ah, const unsigned short* __restrict__ Al,
        const unsigned short* __restrict__ Bh, const unsigned short* __restrict__ Bl,
        const float* __restrict__ x, unsigned short* __restrict__ Xh,
        unsigned short* __restrict__ outH) {
  constexpr int K = 1024, N = 1024;
  __shared__ unsigned short lds[4][64 * 32];   // Ah|Al|Bh|Bl tiles, 16 KB

  const int blk = blockIdx.x, tid = threadIdx.x;

  if (blk >= 256) {   // ---- x -> f16 stream (8388608 float4) ----
    const int i = (blk - 256) * 256 + tid;
    float4 v = ((const float4*)x)[i];
    ushort4 h;
    h.x = f2h(v.x); h.y = f2h(v.y); h.z = f2h(v.z); h.w = f2h(v.w);
    ((ushort4*)Xh)[i] = h;
    return;
  }

  // ---- weight GEMM: 64x64 tile, 4 waves in 2x2, full K ----
  const int mt = blk & 15, nt = blk >> 4;
  const int m0 = mt * 64, n0 = nt * 64;

  const int lane = tid & 63, wave = tid >> 6;
  const int wm = (wave >> 1) * 32, wn = (wave & 1) * 32;
  const int quad = lane >> 4, r = lane & 15;
  const int cs = (quad ^ ((r >> 1) & 3)) * 8;          // swizzled read col
  const int srow = tid >> 2;                           // 0..63
  const int sslot = (tid & 3) ^ ((tid >> 3) & 3);      // inverse-swz source

  const unsigned short* gAh = Ah + (size_t)(m0 + srow) * K + sslot * 8;
  const unsigned short* gAl = Al + (size_t)(m0 + srow) * K + sslot * 8;
  const unsigned short* gBh = Bh + (size_t)(n0 + srow) * K + sslot * 8;
  const unsigned short* gBl = Bl + (size_t)(n0 + srow) * K + sslot * 8;

  v4f acc[2][2];
#pragma unroll
  for (int i = 0; i < 2; ++i)
#pragma unroll
    for (int j = 0; j < 2; ++j) acc[i][j] = v4f{0.f, 0.f, 0.f, 0.f};

  for (int kt = 0; kt < K; kt += 32) {
    gld_lds16(gAh + kt, &lds[0][tid * 8]);
    gld_lds16(gAl + kt, &lds[1][tid * 8]);
    gld_lds16(gBh + kt, &lds[2][tid * 8]);
    gld_lds16(gBl + kt, &lds[3][tid * 8]);
    __syncthreads();

    v8s ah[2], al[2], bh[2], bl[2];
#pragma unroll
    for (int i = 0; i < 2; ++i) {
      ah[i] = *(const v8s*)&lds[0][(wm + i * 16 + r) * 32 + cs];
      al[i] = *(const v8s*)&lds[1][(wm + i * 16 + r) * 32 + cs];
      bh[i] = *(const v8s*)&lds[2][(wn + i * 16 + r) * 32 + cs];
      bl[i] = *(const v8s*)&lds[3][(wn + i * 16 + r) * 32 + cs];
    }
#pragma unroll
    for (int i = 0; i < 2; ++i)
#pragma unroll
      for (int j = 0; j < 2; ++j) {
        acc[i][j] = __builtin_amdgcn_mfma_f32_16x16x32_bf16(ah[i], bh[j], acc[i][j], 0, 0, 0);
        acc[i][j] = __builtin_amdgcn_mfma_f32_16x16x32_bf16(ah[i], bl[j], acc[i][j], 0, 0, 0);
        acc[i][j] = __builtin_amdgcn_mfma_f32_16x16x32_bf16(al[i], bh[j], acc[i][j], 0, 0, 0);
      }
    __syncthreads();
  }

#pragma unroll
  for (int i = 0; i < 2; ++i)
#pragma unroll
    for (int j = 0; j < 2; ++j) {
      const int gn = n0 + wn + j * 16 + r;
#pragma unroll
      for (int q2 = 0; q2 < 4; ++q2) {
        const int gm = m0 + wm + i * 16 + quad * 4 + q2;
        outH[(size_t)gm * N + gn] = f2h(acc[i][j][q2]);
      }
    }
}

// Main GEMM: Y2(f16) = Xf16 @ Wc(f16)^T + bc. 256x256 tile, 8 waves (2Mx4N)
// each owning 128x64. BK=32, SINGLE B plane -> 32 MFMA/wave/K-step in 2
// phases x 16. Triple-buffered LDS (96 KB). r10 discipline: one-phase-ahead
// ds_reads w/ counted lgkmcnt(4); counted vmcnt(4) at P1 (pf-conditional);
// XOR swizzle both-sides (rule #21); setprio on MFMA.
// [r17-measured: 85.7us / MfmaUtil 32.8 / conflicts 0 -- do not modify]
__global__ void __launch_bounds__(512, 2)
gemm_main(const unsigned short* __restrict__ Ah,
          const unsigned short* __restrict__ Bh,
          const float* __restrict__ bias, unsigned short* __restrict__ outH, int M) {
  constexpr int K = 1024, N = 1024;
  __shared__ unsigned short lA[3][8192];   // 48 KB
  __shared__ unsigned short lB[3][8192];   // 48 KB

  const int tid = threadIdx.x;
  const int band = (M >> 8) >> 3;            // 16 for M=32768
  const int c = blockIdx.x & 7, idx = blockIdx.x >> 3;   // 512 blocks, %8==0
  const int mt = c * band + (idx >> 2), nt = idx & 3;
  const int m0 = mt * 256, n0 = nt * 256;

  const int lane = tid & 63, wave = tid >> 6;
  const int wm = (wave >> 2) * 128, wn = (wave & 3) * 64;
  const int quad = lane >> 4, r = lane & 15;
  // swizzled read column (shorts): physical slot = quad ^ ((row>>1)&3)
  const int cs = (quad ^ ((r >> 1) & 3)) * 8;
  const int aoff = (wm + r) * 32 + cs;   // + i*512 per fragment
  const int boff = (wn + r) * 32 + cs;   // + j*512 per fragment

  // staging: thread t -> tile row t>>2, linear LDS slot t&3; global source
  // slot inverse-swizzled so the LDS image is the swizzled layout.
  const int srow = tid >> 2;                           // 0..127 (+128 call 1)
  const int sslot = (tid & 3) ^ ((tid >> 3) & 3);      // same for row+128

  const unsigned short* gA = Ah + (size_t)(m0 + srow) * K + sslot * 8;
  const unsigned short* gB = Bh + (size_t)(n0 + srow) * K + sslot * 8;

  v4f acc[8][4];
#pragma unroll
  for (int i = 0; i < 8; ++i)
#pragma unroll
    for (int j = 0; j < 4; ++j) acc[i][j] = v4f{0.f, 0.f, 0.f, 0.f};

  // buffer rotation pointers: cur / nxt / nx2 (staging target)
  unsigned short *Ac = lA[0], *An = lA[1], *A2 = lA[2];
  unsigned short *Bc = lB[0], *Bn = lB[1], *B2 = lB[2];

  // prologue: stage K-step 0 -> buf0, K-step 1 -> buf1 (4 loads each)
  gld_lds16(gA,             &Ac[tid * 8]);
  gld_lds16(gA + 128 * K,   &Ac[4096 + tid * 8]);
  gld_lds16(gB,             &Bc[tid * 8]);
  gld_lds16(gB + 128 * K,   &Bc[4096 + tid * 8]);
  gld_lds16(gA + 32,            &An[tid * 8]);
  gld_lds16(gA + 32 + 128 * K,  &An[4096 + tid * 8]);
  gld_lds16(gB + 32,            &Bn[tid * 8]);
  gld_lds16(gB + 32 + 128 * K,  &Bn[4096 + tid * 8]);
  asm volatile("s_waitcnt vmcnt(4)" ::: "memory");   // buf0 complete
  __builtin_amdgcn_s_barrier();
  SB;

  // preload K-step 0 operands (8 reads; confirmed by first P0's lgkm(4))
  v8h ah[4], bh[4];
#pragma unroll
  for (int i = 0; i < 4; ++i) ah[i] = *(const v8h*)&Ac[aoff + i * 512];
#pragma unroll
  for (int j = 0; j < 4; ++j) bh[j] = *(const v8h*)&Bc[boff + j * 512];
  SB;

#pragma unroll 1
  for (int t = 0; t < 32; ++t) {
    const int kp = (t + 2) * 32;
    const bool pf = (t < 30);
    v8h ah2[4], anx[4], bnx[4];

    // ---- P0: read ah2(cur); stage A -> nx2; MFMA ah x bh ----
#pragma unroll
    for (int i = 0; i < 4; ++i) ah2[i] = *(const v8h*)&Ac[aoff + (4 + i) * 512];
    if (pf) {
      gld_lds16(gA + kp,           &A2[tid * 8]);
      gld_lds16(gA + kp + 128 * K, &A2[4096 + tid * 8]);
    }
    SB;
    __builtin_amdgcn_s_barrier();
    asm volatile("s_waitcnt lgkmcnt(4)" ::: "memory");  // ah,bh ready; ah2 in flight
    SB;
    __builtin_amdgcn_s_setprio(1);
#pragma unroll
    for (int i = 0; i < 4; ++i)
#pragma unroll
      for (int j = 0; j < 4; ++j)
        acc[i][j] = __builtin_amdgcn_mfma_f32_16x16x32_f16(ah[i], bh[j], acc[i][j], 0, 0, 0);
    __builtin_amdgcn_s_setprio(0);
    SB;
    __builtin_amdgcn_s_barrier();

    // ---- P1: stage B -> nx2; confirm buf nxt; read next K-step operands;
    //          MFMA ah2 x bh ----
    if (pf) {
      gld_lds16(gB + kp,           &B2[tid * 8]);
      gld_lds16(gB + kp + 128 * K, &B2[4096 + tid * 8]);
    }
    SB;
    __builtin_amdgcn_s_barrier();
    // vmcnt(4): 4 newest = this iter's A+B stages; older (buf nxt's 4)
    // confirmed -> An/Bn readable. lgkmcnt(0): ah2 confirmed (cheap).
    if (pf) asm volatile("s_waitcnt vmcnt(4) lgkmcnt(0)" ::: "memory");
    else    asm volatile("s_waitcnt vmcnt(0) lgkmcnt(0)" ::: "memory");
    SB;
#pragma unroll
    for (int i = 0; i < 4; ++i) anx[i] = *(const v8h*)&An[aoff + i * 512];
#pragma unroll
    for (int j = 0; j < 4; ++j) bnx[j] = *(const v8h*)&Bn[boff + j * 512];
    __builtin_amdgcn_s_setprio(1);
#pragma unroll
    for (int i = 0; i < 4; ++i)
#pragma unroll
      for (int j = 0; j < 4; ++j)
        acc[4 + i][j] = __builtin_amdgcn_mfma_f32_16x16x32_f16(ah2[i], bh[j], acc[4 + i][j], 0, 0, 0);
    __builtin_amdgcn_s_setprio(0);
    SB;
    __builtin_amdgcn_s_barrier();

    // rotate buffers; promote prefetched operands
    unsigned short* tp;
    tp = Ac; Ac = An; An = A2; A2 = tp;
    tp = Bc; Bc = Bn; Bn = B2; B2 = tp;
#pragma unroll
    for (int i = 0; i < 4; ++i) { ah[i] = anx[i]; bh[i] = bnx[i]; }
  }

  // epilogue: C[m = quad*4+q2][n = lane&15]; store f16 with bias
  float bv[4];
#pragma unroll
  for (int j = 0; j < 4; ++j) bv[j] = bias[n0 + wn + j * 16 + r];
#pragma unroll
  for (int i = 0; i < 8; ++i)
#pragma unroll
    for (int j = 0; j < 4; ++j) {
      const int gn = n0 + wn + j * 16 + r;
#pragma unroll
      for (int q2 = 0; q2 < 4; ++q2) {
        const int gm = m0 + wm + i * 16 + quad * 4 + q2;
        outH[(size_t)gm * N + gn] = f2h(acc[i][j][q2] + bv[j]);
      }
    }
}

// Fused LIF + head, CHUNK-PARALLEL: 1024 blocks = 32 b x 8 chunks x 4
// quarters, 256 thr (1 channel each) = 16 waves/CU. Chunks 1-7 shadow 32
// warm-up steps (residual 0.5^32 ~ 2e-10; validated r0-r16). Spike counts
// additive across chunks -> per-block partial pooled.W -> wave shfl reduce
// -> LDS across 4 waves -> one atomicAdd per (block, o). b_out added by the
// chunk-0/quarter-0 block only. out zero-init'd in prep.
__global__ void __launch_bounds__(256) lif_head_kernel(
    const unsigned short* __restrict__ y2, const float* __restrict__ W_out,
    const float* __restrict__ b_out, float* __restrict__ out) {
  const int blk = blockIdx.x;               // b*32 + chunk*4 + qg
  const int b = blk >> 5, chunk = (blk >> 2) & 7, qg = blk & 3;
  const int ch = qg * 256 + threadIdx.x;
  const unsigned short* p = y2 + ((size_t)b << 20) + ch;
  const int t0 = chunk << 7;

  float v = 0.f;
  if (chunk) {  // uniform per block
    const unsigned short* pw = p + (size_t)(t0 - 32) * 1024;
    for (int tb = 0; tb < 32; tb += 16) {
      unsigned short xr[16];
#pragma unroll
      for (int i = 0; i < 16; ++i) xr[i] = pw[(size_t)(tb + i) * 1024];
#pragma unroll
      for (int i = 0; i < 16; ++i) {
        v += (h2f(xr[i]) - v) * 0.5f;
        if (v >= 1.0f) v -= 1.0f;
      }
    }
  }
  float cnt = 0.f;
  const unsigned short* pm = p + (size_t)t0 * 1024;
  for (int tb = 0; tb < 128; tb += 16) {
    unsigned short xr[16];
#pragma unroll
    for (int i = 0; i < 16; ++i) xr[i] = pm[(size_t)(tb + i) * 1024];
#pragma unroll
    for (int i = 0; i < 16; ++i) {
      v += (h2f(xr[i]) - v) * 0.5f;          // exact reference op order
      float s = (v >= 1.0f) ? 1.0f : 0.0f;
      cnt += s;
      v -= s;
    }
  }

  // head: partial contribution of this (chunk, channel-quarter)
  const float pooled = cnt * (1.0f / 1024.0f);   // exact (int * 2^-10)
  float pp[10];
#pragma unroll
  for (int o = 0; o < 10; ++o) pp[o] = pooled * W_out[o * 1024 + ch];
#pragma unroll
  for (int o = 0; o < 10; ++o)
#pragma unroll
    for (int off = 32; off > 0; off >>= 1) pp[o] += __shfl_down(pp[o], off);

  __shared__ float ls[4][10];
  const int lane = threadIdx.x & 63, wv = threadIdx.x >> 6;
  if (lane == 0)
#pragma unroll
    for (int o = 0; o < 10; ++o) ls[wv][o] = pp[o];
  __syncthreads();
  if (threadIdx.x < 10) {
    float s = ls[0][threadIdx.x] + ls[1][threadIdx.x] +
              ls[2][threadIdx.x] + ls[3][threadIdx.x];
    if ((blk & 31) == 0) s += b_out[threadIdx.x];   // chunk==0 && qg==0
    atomicAdd(&out[b * 10 + threadIdx.x], s);
  }
}

extern "C" void kernel_launch(void* const* d_in, const int* in_sizes, int n_in,
                              void* d_out, int out_size, void* d_ws, size_t ws_size,
                              hipStream_t stream) {
  const float* x      = (const float*)d_in[0];
  const float* W_proj = (const float*)d_in[1];
  const float* b_proj = (const float*)d_in[2];
  const float* W_hid  = (const float*)d_in[3];
  const float* b_hid  = (const float*)d_in[4];
  const float* W_out  = (const float*)d_in[5];
  const float* b_out  = (const float*)d_in[6];
  float* out = (float*)d_out;

  const int M = 32768;  // B*T

  // Workspace (~141 MB): Xh f16 [64M] | Y2 f16 [64M] | weights | bc
  char* ws = (char*)d_ws;
  unsigned short* Xh   = (unsigned short*)(ws);
  unsigned short* Y2   = (unsigned short*)(ws + 67108864);
  char* base = ws + 134217728;
  unsigned short* WpTh = (unsigned short*)(base);             // bf16
  unsigned short* WpTl = (unsigned short*)(base + 2097152);
  unsigned short* Whh  = (unsigned short*)(base + 4194304);
  unsigned short* Whl  = (unsigned short*)(base + 6291456);
  unsigned short* Wch  = (unsigned short*)(base + 8388608);   // f16 (single)
  float*           bc  = (float*)(base + 10485760);

  prep_kernel<<<2305, 256, 0, stream>>>(W_proj, W_hid, b_proj, b_hid,
                                        WpTh, WpTl, Whh, Whl, bc, out);
  // Wc[g,d] = sum_h Wh[g,h] * WpT[d,h] (blocks 0..255) || x->Xh (rest)
  gemm_wx<<<33024, 256, 0, stream>>>(Whh, Whl, WpTh, WpTl, x, Xh, Wch);
  gemm_main<<<512, 512, 0, stream>>>(Xh, Wch, bc, Y2, M);
  lif_head_kernel<<<1024, 256, 0, stream>>>(Y2, W_out, b_out, out);
}